// Round 7
// baseline (2871.878 us; speedup 1.0000x reference)
//
#include <hip/hip_runtime.h>
#include <math.h>

#ifndef M_PI
#define M_PI 3.14159265358979323846
#endif

// ============================================================================
// Decision path replicates numpy-float32 semantics:
//  - vec_norm: numpy pairwise sum (128-blocks, 8 accumulators, balanced tree)
//  - k_n = keys / (norm + 1e-8f): correctly-rounded f32 division
//  - y = k_n @ Pi.T, P = res @ S.T: ONE sequential-k FMA chain per element
//    (round-7 experiment: no KC-panel breaks; KC template kept for sweeps)
//  - argmin / residual in f32 with no FP contraction
// Continuous path (q_rot, z, term1/term2, final scale) stays f64.
// ============================================================================

#define KC_PANEL 1048576   // no panel breaks this round

// ---------------------------------------------------------------------------
// numpy-exact row norms of keys (4096 x 2048), 16 rows/block, 16 thr/row.
// den[r] = nrm + 1e-8f (f32), vnorm[r] = nrm (f32)
// ---------------------------------------------------------------------------
__global__ __launch_bounds__(256)
void norm_np_k(const float* __restrict__ keys,
               float* __restrict__ den,
               float* __restrict__ vnorm)
{
#pragma clang fp contract(off)
    const int tid = threadIdx.x;
    const int row_l = tid >> 4;
    const int blk = tid & 15;
    const int row = blockIdx.x * 16 + row_l;
    const float* a = keys + (size_t)row * 2048 + blk * 128;

    float r0 = a[0]*a[0], r1 = a[1]*a[1], r2 = a[2]*a[2], r3 = a[3]*a[3];
    float r4 = a[4]*a[4], r5 = a[5]*a[5], r6 = a[6]*a[6], r7 = a[7]*a[7];
    for (int i = 8; i < 128; i += 8) {
        r0 += a[i+0]*a[i+0]; r1 += a[i+1]*a[i+1];
        r2 += a[i+2]*a[i+2]; r3 += a[i+3]*a[i+3];
        r4 += a[i+4]*a[i+4]; r5 += a[i+5]*a[i+5];
        r6 += a[i+6]*a[i+6]; r7 += a[i+7]*a[i+7];
    }
    float bsum = ((r0 + r1) + (r2 + r3)) + ((r4 + r5) + (r6 + r7));

    __shared__ float bs[16][16];
    bs[row_l][blk] = bsum;
    __syncthreads();
    if (blk == 0) {
        const float* b = bs[row_l];
        float q0 = ((b[0] + b[1]) + (b[2] + b[3])) + ((b[4] + b[5]) + (b[6] + b[7]));
        float q1 = ((b[8] + b[9]) + (b[10] + b[11])) + ((b[12] + b[13]) + (b[14] + b[15]));
        float s = q0 + q1;
        float n = (float)sqrt((double)s);
        den[row] = n + 1e-8f;
        vnorm[row] = n;
    }
}

// ---------------------------------------------------------------------------
// k_n chunk: kn[j,d] = keys[r0+j,d] / den[r0+j]  (f32 correctly-rounded div)
// ---------------------------------------------------------------------------
__global__ __launch_bounds__(256)
void kn_k(const float* __restrict__ keys_c,
          const float* __restrict__ den_c,
          float* __restrict__ kn)
{
#pragma clang fp contract(off)
    const int idx = (blockIdx.x * 256 + threadIdx.x) * 8;
    const int row = idx >> 11;
    const float d = den_c[row];
    float4 v0 = *(const float4*)(keys_c + idx);
    float4 v1 = *(const float4*)(keys_c + idx + 4);
    v0.x /= d; v0.y /= d; v0.z /= d; v0.w /= d;
    v1.x /= d; v1.y /= d; v1.z /= d; v1.w /= d;
    *(float4*)(kn + idx) = v0;
    *(float4*)(kn + idx + 4) = v1;
}

// ---------------------------------------------------------------------------
// Decision-path f32 GEMM: C = A(MxK) @ B(NxK)^T.
// Per element: sequential-k fmaf chain; optional restart at KC boundaries
// (disabled this round via KC huge).
//   EPI 0: C[r,c] = total (f32)
//   EPI 1: C[r,c] = sign(total) * rv[r]
// ---------------------------------------------------------------------------
template <int KC, int EPI>
__global__ __launch_bounds__(256)
void gemm_np_k(const float* __restrict__ A, int lda,
               const float* __restrict__ B, int ldb,
               float* __restrict__ C, int ldc, int K,
               const float* __restrict__ rv)
{
#pragma clang fp contract(off)
    __shared__ float At[64][65];
    __shared__ float Bt[64][65];

    const int tid = threadIdx.x;
    const int tr = tid >> 4;
    const int tc = tid & 15;
    const int row0 = blockIdx.y * 64;
    const int col0 = blockIdx.x * 64;

    float total[4][4] = {};
    float pacc[4][4] = {};

    for (int d0 = 0; d0 < K; d0 += 64) {
        #pragma unroll
        for (int u = 0; u < 4; ++u) {
            int idx = tid + u * 256;
            int r = idx >> 4;
            int cb = (idx & 15) * 4;
            float4 va = *(const float4*)(A + (size_t)(row0 + r) * lda + d0 + cb);
            At[r][cb+0] = va.x; At[r][cb+1] = va.y; At[r][cb+2] = va.z; At[r][cb+3] = va.w;
            float4 vb = *(const float4*)(B + (size_t)(col0 + r) * ldb + d0 + cb);
            Bt[r][cb+0] = vb.x; Bt[r][cb+1] = vb.y; Bt[r][cb+2] = vb.z; Bt[r][cb+3] = vb.w;
        }
        __syncthreads();

        if (d0 > 0 && (d0 % KC) == 0) {
            #pragma unroll
            for (int i = 0; i < 4; ++i)
                #pragma unroll
                for (int j = 0; j < 4; ++j) {
                    total[i][j] = total[i][j] + pacc[i][j];
                    pacc[i][j] = 0.0f;
                }
        }

        #pragma unroll 4
        for (int d = 0; d < 64; ++d) {
            float a[4], b[4];
            #pragma unroll
            for (int i = 0; i < 4; ++i) a[i] = At[tr * 4 + i][d];
            #pragma unroll
            for (int j = 0; j < 4; ++j) b[j] = Bt[tc * 4 + j][d];
            #pragma unroll
            for (int i = 0; i < 4; ++i)
                #pragma unroll
                for (int j = 0; j < 4; ++j)
                    pacc[i][j] = fmaf(a[i], b[j], pacc[i][j]);
        }
        __syncthreads();
    }

    #pragma unroll
    for (int i = 0; i < 4; ++i) {
        const int r = row0 + tr * 4 + i;
        #pragma unroll
        for (int j = 0; j < 4; ++j) {
            const int c = col0 + tc * 4 + j;
            float t = total[i][j] + pacc[i][j];
            if (EPI == 0) {
                C[(size_t)r * ldc + c] = t;
            } else {
                float s = (t > 0.0f) ? 1.0f : ((t < 0.0f) ? -1.0f : 0.0f);
                C[(size_t)r * ldc + c] = s * rv[r];
            }
        }
    }
}

// ---------------------------------------------------------------------------
// Quantize one key row (f32, numpy-exact): nearest centroid (first-min ties),
// residual in place, y_mse out, numpy-pairwise residual norms ->
// sc = coef * rn * vnorm.
// ---------------------------------------------------------------------------
__global__ __launch_bounds__(256)
void quant_np_k(float* __restrict__ Y,
                float* __restrict__ Ymse,
                const float* __restrict__ ch,
                const float* __restrict__ cl,
                const float* __restrict__ vnorm_c,
                float* __restrict__ sc_h,
                float* __restrict__ sc_l,
                double coefd)
{
#pragma clang fp contract(off)
    __shared__ float resq[2048];
    __shared__ float bs[16];

    const int row = blockIdx.x;
    const int tid = threadIdx.x;
    const int c0 = tid * 8;
    const float h0 = ch[0], h1 = ch[1], h2 = ch[2], h3 = ch[3];
    const float l0 = cl[0], l1 = cl[1];

    float y[8], res[8], cc[8];
    *(float4*)(y)     = *(const float4*)(Y + (size_t)row * 2048 + c0);
    *(float4*)(y + 4) = *(const float4*)(Y + (size_t)row * 2048 + c0 + 4);

    const bool high = (tid < 128);
    #pragma unroll
    for (int j = 0; j < 8; ++j) {
        float v = y[j], cbest;
        if (high) {
            cbest = h0;
            float bd = fabsf(v - h0), dd;
            dd = fabsf(v - h1); if (dd < bd) { bd = dd; cbest = h1; }
            dd = fabsf(v - h2); if (dd < bd) { bd = dd; cbest = h2; }
            dd = fabsf(v - h3); if (dd < bd) { bd = dd; cbest = h3; }
        } else {
            cbest = (fabsf(v - l1) < fabsf(v - l0)) ? l1 : l0;
        }
        cc[j] = cbest;
        res[j] = v - cbest;
        resq[c0 + j] = res[j] * res[j];
    }
    *(float4*)(Y + (size_t)row * 2048 + c0)     = *(float4*)(res);
    *(float4*)(Y + (size_t)row * 2048 + c0 + 4) = *(float4*)(res + 4);
    *(float4*)(Ymse + (size_t)row * 2048 + c0)     = *(float4*)(cc);
    *(float4*)(Ymse + (size_t)row * 2048 + c0 + 4) = *(float4*)(cc + 4);
    __syncthreads();

    if (tid < 16) {
        const float* a = resq + tid * 128;
        float r0 = a[0], r1 = a[1], r2 = a[2], r3 = a[3];
        float r4 = a[4], r5 = a[5], r6 = a[6], r7 = a[7];
        for (int i = 8; i < 128; i += 8) {
            r0 += a[i+0]; r1 += a[i+1]; r2 += a[i+2]; r3 += a[i+3];
            r4 += a[i+4]; r5 += a[i+5]; r6 += a[i+6]; r7 += a[i+7];
        }
        bs[tid] = ((r0 + r1) + (r2 + r3)) + ((r4 + r5) + (r6 + r7));
    }
    __syncthreads();
    if (tid == 0) {
        float sh = ((bs[0] + bs[1]) + (bs[2] + bs[3])) + ((bs[4] + bs[5]) + (bs[6] + bs[7]));
        float sl = ((bs[8] + bs[9]) + (bs[10] + bs[11])) + ((bs[12] + bs[13]) + (bs[14] + bs[15]));
        float rnh = (float)sqrt((double)sh);
        float rnl = (float)sqrt((double)sl);
        double vn = (double)vnorm_c[row];
        sc_h[row] = (float)(coefd * (double)rnh * vn);
        sc_l[row] = (float)(coefd * (double)rnl * vn);
    }
}

// ---------------------------------------------------------------------------
// Continuous-path tiled GEMM (f64 accumulate): C = A(MxK) @ B(NxK)^T
//   EPI 0: C_f32 = (float)acc
//       3: C_f32 = (float)acc * cv_f[c]
//       4: C_f32 += (float)acc
// ---------------------------------------------------------------------------
template <int EPI>
__global__ __launch_bounds__(256)
void gemm2_k(const float* __restrict__ A, int lda,
             const float* __restrict__ B, int ldb,
             float* __restrict__ C, int ldc, int K,
             const float* __restrict__ cv_f)
{
    __shared__ float As[64][33];
    __shared__ float Bs[64][33];

    const int tid = threadIdx.x;
    const int tr = tid >> 4;
    const int tc = tid & 15;
    const int row0 = blockIdx.y * 64;
    const int col0 = blockIdx.x * 64;

    double acc[4][4] = {};

    for (int k0 = 0; k0 < K; k0 += 32) {
        {
            const int r = tid >> 2;
            const int cb = (tid & 3) * 8;
            const float* sa = A + (size_t)(row0 + r) * lda + k0 + cb;
            #pragma unroll
            for (int u = 0; u < 8; ++u) As[r][cb + u] = sa[u];
            const float* sb = B + (size_t)(col0 + r) * ldb + k0 + cb;
            #pragma unroll
            for (int u = 0; u < 8; ++u) Bs[r][cb + u] = sb[u];
        }
        __syncthreads();

        #pragma unroll
        for (int kk = 0; kk < 32; ++kk) {
            double a[4], b[4];
            #pragma unroll
            for (int i = 0; i < 4; ++i) a[i] = (double)As[tr * 4 + i][kk];
            #pragma unroll
            for (int j = 0; j < 4; ++j) b[j] = (double)Bs[tc * 4 + j][kk];
            #pragma unroll
            for (int i = 0; i < 4; ++i)
                #pragma unroll
                for (int j = 0; j < 4; ++j)
                    acc[i][j] = fma(a[i], b[j], acc[i][j]);
        }
        __syncthreads();
    }

    #pragma unroll
    for (int i = 0; i < 4; ++i) {
        const int r = row0 + tr * 4 + i;
        #pragma unroll
        for (int j = 0; j < 4; ++j) {
            const int c = col0 + tc * 4 + j;
            const double v = acc[i][j];
            if (EPI == 0)      C[(size_t)r * ldc + c] = (float)v;
            else if (EPI == 3) C[(size_t)r * ldc + c] = (float)v * cv_f[c];
            else               C[(size_t)r * ldc + c] += (float)v;
        }
    }
}

// ---------------------------------------------------------------------------
// Launch. Workspace (< 49 MiB), chunked 4 x 1024 key rows.
// ---------------------------------------------------------------------------
extern "C" void kernel_launch(void* const* d_in, const int* in_sizes, int n_in,
                              void* d_out, int out_size, void* d_ws, size_t ws_size,
                              hipStream_t stream)
{
    const float* queries = (const float*)d_in[0];
    const float* keys    = (const float*)d_in[1];
    const float* Pi      = (const float*)d_in[2];
    const float* ch      = (const float*)d_in[3];
    const float* cl      = (const float*)d_in[4];
    const float* S_high  = (const float*)d_in[5];
    const float* S_low   = (const float*)d_in[6];
    float* out = (float*)d_out;

    char* ws = (char*)d_ws;
    float* kn_c    = (float*)(ws);
    float* y_c     = (float*)(ws + ((size_t)8 << 20));
    float* Ymse_c  = (float*)(ws + ((size_t)16 << 20));
    float* sgnsc_c = (float*)(ws + ((size_t)24 << 20));
    float* Abig    = (float*)(ws + ((size_t)32 << 20));
    float* den     = (float*)(ws + ((size_t)48 << 20));
    float* vnorm   = (float*)(ws + ((size_t)48 << 20) + 16384);
    float* sc_h    = (float*)(ws + ((size_t)48 << 20) + 32768);
    float* sc_l    = (float*)(ws + ((size_t)48 << 20) + 49152);

    const double coefd = sqrt(M_PI / 2.0) / 1024.0;

    // numpy-exact norms
    norm_np_k<<<256, 256, 0, stream>>>(keys, den, vnorm);

    // continuous q-side: Abig = [q_rot | qh@S_h^T | ql@S_l^T]
    gemm2_k<0><<<dim3(32, 16), 256, 0, stream>>>(
        queries, 2048, Pi, 2048, Abig, 4096, 2048, nullptr);
    gemm2_k<0><<<dim3(16, 16), 256, 0, stream>>>(
        Abig, 4096, S_high, 1024, Abig + 2048, 4096, 1024, nullptr);
    gemm2_k<0><<<dim3(16, 16), 256, 0, stream>>>(
        Abig + 1024, 4096, S_low, 1024, Abig + 3072, 4096, 1024, nullptr);

    for (int g = 0; g < 4; ++g) {
        const int r0 = g * 1024;

        // k_n chunk (np-exact f32 division)
        kn_k<<<1024, 256, 0, stream>>>(keys + (size_t)r0 * 2048, den + r0, kn_c);

        // y chunk = kn_c @ Pi^T  (f32 single sequential FMA chain)
        gemm_np_k<KC_PANEL, 0><<<dim3(32, 16), 256, 0, stream>>>(
            kn_c, 2048, Pi, 2048, y_c, 2048, 2048, nullptr);

        // quantize (np-exact): residual in y_c, Ymse_c, sc_h/sc_l
        quant_np_k<<<1024, 256, 0, stream>>>(
            y_c, Ymse_c, ch, cl, vnorm + r0, sc_h, sc_l, coefd);

        // scaled signs (f32 single sequential FMA chain)
        gemm_np_k<KC_PANEL, 1><<<dim3(16, 16), 256, 0, stream>>>(
            y_c, 2048, S_high, 1024, sgnsc_c, 2048, 1024, sc_h);
        gemm_np_k<KC_PANEL, 1><<<dim3(16, 16), 256, 0, stream>>>(
            y_c + 1024, 2048, S_low, 1024, sgnsc_c + 1024, 2048, 1024, sc_l);

        // out[:, r0:r0+1024] = (q_rot @ y_mse^T) * vnorm[col]
        gemm2_k<3><<<dim3(16, 16), 256, 0, stream>>>(
            Abig, 4096, Ymse_c, 2048, out + r0, 4096, 2048, vnorm + r0);

        // out += z_h @ sgnsc_h^T ; out += z_l @ sgnsc_l^T
        gemm2_k<4><<<dim3(16, 16), 256, 0, stream>>>(
            Abig + 2048, 4096, sgnsc_c, 2048, out + r0, 4096, 1024, nullptr);
        gemm2_k<4><<<dim3(16, 16), 256, 0, stream>>>(
            Abig + 3072, 4096, sgnsc_c + 1024, 2048, out + r0, 4096, 1024, nullptr);
    }
}

// Round 8
// 940.925 us; speedup vs baseline: 3.0522x; 3.0522x over previous
//
#include <hip/hip_runtime.h>
#include <math.h>

#ifndef M_PI
#define M_PI 3.14159265358979323846
#endif

typedef __attribute__((ext_vector_type(8))) __bf16 bf16x8;
typedef __attribute__((ext_vector_type(4))) float f32x4;
typedef __attribute__((ext_vector_type(8))) unsigned short ushort8;

__device__ __forceinline__ unsigned short f2bf(float x) {
    unsigned int u = __float_as_uint(x);
    unsigned int r = (u + 0x7FFFu + ((u >> 16) & 1u)) >> 16;
    return (unsigned short)r;
}

// ---------------------------------------------------------------------------
// numpy-exact row norms of keys (4096 x 2048), 16 rows/block, 16 thr/row.
// den[r] = nrm + 1e-8f (decision path), vnorm[r] = nrm (continuous colscale)
// ---------------------------------------------------------------------------
__global__ __launch_bounds__(256)
void norm_np_k(const float* __restrict__ keys,
               float* __restrict__ den,
               float* __restrict__ vnorm)
{
#pragma clang fp contract(off)
    const int tid = threadIdx.x;
    const int row_l = tid >> 4;
    const int blk = tid & 15;
    const int row = blockIdx.x * 16 + row_l;
    const float* a = keys + (size_t)row * 2048 + blk * 128;

    float r0 = a[0]*a[0], r1 = a[1]*a[1], r2 = a[2]*a[2], r3 = a[3]*a[3];
    float r4 = a[4]*a[4], r5 = a[5]*a[5], r6 = a[6]*a[6], r7 = a[7]*a[7];
    for (int i = 8; i < 128; i += 8) {
        r0 += a[i+0]*a[i+0]; r1 += a[i+1]*a[i+1];
        r2 += a[i+2]*a[i+2]; r3 += a[i+3]*a[i+3];
        r4 += a[i+4]*a[i+4]; r5 += a[i+5]*a[i+5];
        r6 += a[i+6]*a[i+6]; r7 += a[i+7]*a[i+7];
    }
    float bsum = ((r0 + r1) + (r2 + r3)) + ((r4 + r5) + (r6 + r7));

    __shared__ float bs[16][16];
    bs[row_l][blk] = bsum;
    __syncthreads();
    if (blk == 0) {
        const float* b = bs[row_l];
        float q0 = ((b[0] + b[1]) + (b[2] + b[3])) + ((b[4] + b[5]) + (b[6] + b[7]));
        float q1 = ((b[8] + b[9]) + (b[10] + b[11])) + ((b[12] + b[13]) + (b[14] + b[15]));
        float s = q0 + q1;
        float n = (float)sqrt((double)s);
        den[row] = n + 1e-8f;
        vnorm[row] = n;
    }
}

// ---------------------------------------------------------------------------
// f32 -> bf16 conversion (RNE), 8 elements/thread, exact-size grid.
// ---------------------------------------------------------------------------
__global__ __launch_bounds__(256)
void f2bf_k(const float* __restrict__ in, unsigned short* __restrict__ out)
{
    const int i = (blockIdx.x * 256 + threadIdx.x) * 8;
    float4 v0 = *(const float4*)(in + i);
    float4 v1 = *(const float4*)(in + i + 4);
    ushort8 o;
    o[0] = f2bf(v0.x); o[1] = f2bf(v0.y); o[2] = f2bf(v0.z); o[3] = f2bf(v0.w);
    o[4] = f2bf(v1.x); o[5] = f2bf(v1.y); o[6] = f2bf(v1.z); o[7] = f2bf(v1.w);
    *(ushort8*)(out + i) = o;
}

// ---------------------------------------------------------------------------
// Decision-path f32 GEMM (bitwise numpy-f32 chain): C = A(MxK) @ B(NxK)^T.
// Per output element: ONE sequential-k fmaf chain (no breaks), contract off.
// 128x128 tile, 256 threads, 8x8 outputs/thread, k-transposed LDS.
//   DIVA: A elements are divided by dena[row] at staging (correctly-rounded
//         f32 div == precomputing kn; bitwise identical).
//   EPI 0: Cf[r,c] = total (f32)
//   EPI 1: Cb[r,c] = bf16( sign(total) * rv[r] )   (scaled signs, continuous
//          scale rv so bf16 rounding is allowed)
// ---------------------------------------------------------------------------
template <int EPI, int DIVA>
__global__ __launch_bounds__(256)
void gemm_dec_k(const float* __restrict__ A, int lda,
                const float* __restrict__ B, int ldb,
                float* __restrict__ Cf, unsigned short* __restrict__ Cb,
                int ldc, int K,
                const float* __restrict__ dena,
                const float* __restrict__ rv)
{
#pragma clang fp contract(off)
    __shared__ float As[16][132];   // [k][row], pad 4 -> conflict-free writes
    __shared__ float Bs[16][132];

    const int tid = threadIdx.x;
    const int tr = tid >> 4;            // 0..15  (8 rows each)
    const int tc = tid & 15;            // 0..15  (8 cols each)
    const int row0 = blockIdx.y * 128;
    const int col0 = blockIdx.x * 128;
    const int sr = tid >> 1;            // staging row 0..127
    const int sk = (tid & 1) * 8;       // staging k-offset 0/8

    const float dv = DIVA ? dena[row0 + sr] : 1.0f;
    const float* ga = A + (size_t)(row0 + sr) * lda + sk;
    const float* gb = B + (size_t)(col0 + sr) * ldb + sk;

    float acc[8][8] = {};

    for (int k0 = 0; k0 < K; k0 += 16) {
        float av[8], bv[8];
        *(float4*)(av)     = *(const float4*)(ga + k0);
        *(float4*)(av + 4) = *(const float4*)(ga + k0 + 4);
        *(float4*)(bv)     = *(const float4*)(gb + k0);
        *(float4*)(bv + 4) = *(const float4*)(gb + k0 + 4);
        if (DIVA) {
            #pragma unroll
            for (int u = 0; u < 8; ++u) av[u] = av[u] / dv;
        }
        __syncthreads();
        #pragma unroll
        for (int u = 0; u < 8; ++u) {
            As[sk + u][sr] = av[u];
            Bs[sk + u][sr] = bv[u];
        }
        __syncthreads();
        #pragma unroll
        for (int kk = 0; kk < 16; ++kk) {
            float a[8], b[8];
            *(float4*)(a)     = *(const float4*)&As[kk][tr * 8];
            *(float4*)(a + 4) = *(const float4*)&As[kk][tr * 8 + 4];
            *(float4*)(b)     = *(const float4*)&Bs[kk][tc * 8];
            *(float4*)(b + 4) = *(const float4*)&Bs[kk][tc * 8 + 4];
            #pragma unroll
            for (int i = 0; i < 8; ++i)
                #pragma unroll
                for (int j = 0; j < 8; ++j)
                    acc[i][j] = fmaf(a[i], b[j], acc[i][j]);
        }
    }

    if (EPI == 0) {
        #pragma unroll
        for (int i = 0; i < 8; ++i) {
            const int r = row0 + tr * 8 + i;
            #pragma unroll
            for (int j = 0; j < 8; ++j)
                Cf[(size_t)r * ldc + col0 + tc * 8 + j] = acc[i][j];
        }
    } else {
        #pragma unroll
        for (int i = 0; i < 8; ++i) {
            const int r = row0 + tr * 8 + i;
            const float s = rv[r];
            #pragma unroll
            for (int j = 0; j < 8; ++j) {
                const float t = acc[i][j];
                const float v = (t > 0.0f) ? s : ((t < 0.0f) ? -s : 0.0f);
                Cb[(size_t)r * ldc + col0 + tc * 8 + j] = f2bf(v);
            }
        }
    }
}

// ---------------------------------------------------------------------------
// Quantize one key row (f32, numpy-exact decisions): nearest centroid
// (first-min ties), residual in place over Y, bf16 y_mse into Bbig[:,0:2048],
// sc = coef * ||res_group||  (continuous; vnorm applied in final colscale).
// ---------------------------------------------------------------------------
__global__ __launch_bounds__(256)
void quant_k(float* __restrict__ Y,
             unsigned short* __restrict__ Bmse,   // ld 4096
             const float* __restrict__ ch,
             const float* __restrict__ cl,
             float* __restrict__ sc_h,
             float* __restrict__ sc_l,
             double coefd)
{
#pragma clang fp contract(off)
    const int row = blockIdx.x;
    const int tid = threadIdx.x;
    const int c0 = tid * 8;
    const float h0 = ch[0], h1 = ch[1], h2 = ch[2], h3 = ch[3];
    const float l0 = cl[0], l1 = cl[1];

    float y[8], res[8];
    ushort8 cb;
    *(float4*)(y)     = *(const float4*)(Y + (size_t)row * 2048 + c0);
    *(float4*)(y + 4) = *(const float4*)(Y + (size_t)row * 2048 + c0 + 4);

    const bool high = (tid < 128);
    float ss = 0.0f;
    #pragma unroll
    for (int j = 0; j < 8; ++j) {
        const float v = y[j];
        float cbest;
        if (high) {
            cbest = h0;
            float bd = fabsf(v - h0), dd;
            dd = fabsf(v - h1); if (dd < bd) { bd = dd; cbest = h1; }
            dd = fabsf(v - h2); if (dd < bd) { bd = dd; cbest = h2; }
            dd = fabsf(v - h3); if (dd < bd) { bd = dd; cbest = h3; }
        } else {
            cbest = (fabsf(v - l1) < fabsf(v - l0)) ? l1 : l0;
        }
        res[j] = v - cbest;
        cb[j] = f2bf(cbest);
        ss += res[j] * res[j];
    }
    *(float4*)(Y + (size_t)row * 2048 + c0)     = *(float4*)(res);
    *(float4*)(Y + (size_t)row * 2048 + c0 + 4) = *(float4*)(res + 4);
    *(ushort8*)(Bmse + (size_t)row * 4096 + c0) = cb;

    __shared__ float sm[256];
    sm[tid] = ss;
    __syncthreads();
    for (int o = 64; o > 0; o >>= 1) {
        if ((tid & 127) < o) sm[tid] += sm[tid + o];
        __syncthreads();
    }
    if (tid == 0)   sc_h[row] = (float)(coefd * sqrt((double)sm[0]));
    if (tid == 128) sc_l[row] = (float)(coefd * sqrt((double)sm[128]));
}

// ---------------------------------------------------------------------------
// Continuous-path bf16 MFMA GEMM: C = A(MxK bf16) @ B(NxK bf16)^T, f32 accum.
// 128x128 tile, 4 waves (2x2), 4x4 16x16x32 fragments per wave.
//   EPI 1: Cf[r,c] = acc * colscale[c]
//   EPI 2: Cb[r,c] = bf16(acc)
// C/D layout (m89-verified): row=(lane>>4)*4+reg, col=lane&15.
// ---------------------------------------------------------------------------
template <int EPI>
__global__ __launch_bounds__(256)
void gemm_mfma_k(const unsigned short* __restrict__ A, int lda,
                 const unsigned short* __restrict__ B, int ldb,
                 float* __restrict__ Cf, unsigned short* __restrict__ Cb,
                 int ldc, int K, const float* __restrict__ colscale)
{
    __shared__ unsigned short As[128][40];   // 32 + 8 pad (80B row stride)
    __shared__ unsigned short Bs[128][40];

    const int tid = threadIdx.x;
    const int lane = tid & 63;
    const int wid = tid >> 6;
    const int wm = wid >> 1;            // 0..1
    const int wn = wid & 1;             // 0..1
    const int row0 = blockIdx.y * 128;
    const int col0 = blockIdx.x * 128;
    const int sr = tid >> 1;            // staging row 0..127
    const int sk = (tid & 1) * 16;      // staging k-offset 0/16
    const int frow = lane & 15;
    const int fk = (lane >> 4) * 8;

    const unsigned short* ga = A + (size_t)(row0 + sr) * lda + sk;
    const unsigned short* gb = B + (size_t)(col0 + sr) * ldb + sk;

    f32x4 acc[4][4] = {};

    for (int k0 = 0; k0 < K; k0 += 32) {
        ushort8 a0 = *(const ushort8*)(ga + k0);
        ushort8 a1 = *(const ushort8*)(ga + k0 + 8);
        ushort8 b0 = *(const ushort8*)(gb + k0);
        ushort8 b1 = *(const ushort8*)(gb + k0 + 8);
        __syncthreads();
        *(ushort8*)&As[sr][sk]     = a0;
        *(ushort8*)&As[sr][sk + 8] = a1;
        *(ushort8*)&Bs[sr][sk]     = b0;
        *(ushort8*)&Bs[sr][sk + 8] = b1;
        __syncthreads();

        bf16x8 af[4], bfr[4];
        #pragma unroll
        for (int mi = 0; mi < 4; ++mi)
            af[mi] = *(const bf16x8*)&As[wm * 64 + mi * 16 + frow][fk];
        #pragma unroll
        for (int ni = 0; ni < 4; ++ni)
            bfr[ni] = *(const bf16x8*)&Bs[wn * 64 + ni * 16 + frow][fk];
        #pragma unroll
        for (int mi = 0; mi < 4; ++mi)
            #pragma unroll
            for (int ni = 0; ni < 4; ++ni)
                acc[mi][ni] = __builtin_amdgcn_mfma_f32_16x16x32_bf16(
                    af[mi], bfr[ni], acc[mi][ni], 0, 0, 0);
    }

    const int drow = (lane >> 4) * 4;
    const int dcol = lane & 15;
    #pragma unroll
    for (int mi = 0; mi < 4; ++mi) {
        #pragma unroll
        for (int ni = 0; ni < 4; ++ni) {
            const int c = col0 + wn * 64 + ni * 16 + dcol;
            const float cs = (EPI == 1) ? colscale[c] : 0.0f;
            #pragma unroll
            for (int rg = 0; rg < 4; ++rg) {
                const int r = row0 + wm * 64 + mi * 16 + drow + rg;
                const float v = acc[mi][ni][rg];
                if (EPI == 1) Cf[(size_t)r * ldc + c] = v * cs;
                else          Cb[(size_t)r * ldc + c] = f2bf(v);
            }
        }
    }
}

// ---------------------------------------------------------------------------
// Launch. Workspace (~88 MB):
//   Y     @  0M : 4096x2048 f32 (y, then residual in place)
//   Bbig  @ 32M : 4096x4096 bf16  [ymse | sgn*sc_h | sgn*sc_l]
//   Abig  @ 64M : 1024x4096 bf16  [q_rot | z_h | z_l]
//   Qb    @ 72M : 1024x2048 bf16
//   Pib   @ 76M : 2048x2048 bf16
//   Sbh   @ 84M, Sbl @ 86M : 1024x1024 bf16
//   den   @ 88M, vnorm +16K, sc_h +32K, sc_l +48K
// ---------------------------------------------------------------------------
extern "C" void kernel_launch(void* const* d_in, const int* in_sizes, int n_in,
                              void* d_out, int out_size, void* d_ws, size_t ws_size,
                              hipStream_t stream)
{
    const float* queries = (const float*)d_in[0];
    const float* keys    = (const float*)d_in[1];
    const float* Pi      = (const float*)d_in[2];
    const float* ch      = (const float*)d_in[3];
    const float* cl      = (const float*)d_in[4];
    const float* S_high  = (const float*)d_in[5];
    const float* S_low   = (const float*)d_in[6];
    float* out = (float*)d_out;

    char* ws = (char*)d_ws;
    float*          Y     = (float*)(ws);
    unsigned short* Bbig  = (unsigned short*)(ws + ((size_t)32 << 20));
    unsigned short* Abig  = (unsigned short*)(ws + ((size_t)64 << 20));
    unsigned short* Qb    = (unsigned short*)(ws + ((size_t)72 << 20));
    unsigned short* Pib   = (unsigned short*)(ws + ((size_t)76 << 20));
    unsigned short* Sbh   = (unsigned short*)(ws + ((size_t)84 << 20));
    unsigned short* Sbl   = (unsigned short*)(ws + ((size_t)86 << 20));
    float*          den   = (float*)(ws + ((size_t)88 << 20));
    float*          vnorm = (float*)(ws + ((size_t)88 << 20) + 16384);
    float*          sc_h  = (float*)(ws + ((size_t)88 << 20) + 32768);
    float*          sc_l  = (float*)(ws + ((size_t)88 << 20) + 49152);

    const double coefd = sqrt(M_PI / 2.0) / 1024.0;

    // numpy-exact norms (decision + continuous colscale)
    norm_np_k<<<256, 256, 0, stream>>>(keys, den, vnorm);

    // bf16 copies for the continuous MFMA path
    f2bf_k<<<1024, 256, 0, stream>>>(queries, Qb);
    f2bf_k<<<2048, 256, 0, stream>>>(Pi, Pib);
    f2bf_k<<<512, 256, 0, stream>>>(S_high, Sbh);
    f2bf_k<<<512, 256, 0, stream>>>(S_low, Sbl);

    // DECISION: Y = (keys/den) @ Pi^T  (f32 exact, fused normalize)
    gemm_dec_k<0, 1><<<dim3(16, 32), 256, 0, stream>>>(
        keys, 2048, Pi, 2048, Y, nullptr, 2048, 2048, den, nullptr);

    // DECISION: quantize -> residual in Y, bf16 ymse in Bbig, sc_h/sc_l
    quant_k<<<4096, 256, 0, stream>>>(Y, Bbig, ch, cl, sc_h, sc_l, coefd);

    // DECISION: scaled signs -> bf16 into Bbig[:,2048:3072] / [:,3072:4096]
    gemm_dec_k<1, 0><<<dim3(8, 32), 256, 0, stream>>>(
        Y, 2048, S_high, 1024, nullptr, Bbig + 2048, 4096, 1024, nullptr, sc_h);
    gemm_dec_k<1, 0><<<dim3(8, 32), 256, 0, stream>>>(
        Y + 1024, 2048, S_low, 1024, nullptr, Bbig + 3072, 4096, 1024, nullptr, sc_l);

    // CONTINUOUS (bf16 MFMA): Abig = [q_rot | z_h | z_l]
    gemm_mfma_k<2><<<dim3(16, 8), 256, 0, stream>>>(
        Qb, 2048, Pib, 2048, nullptr, Abig, 4096, 2048, nullptr);
    gemm_mfma_k<2><<<dim3(8, 8), 256, 0, stream>>>(
        Abig, 4096, Sbh, 1024, nullptr, Abig + 2048, 4096, 1024, nullptr);
    gemm_mfma_k<2><<<dim3(8, 8), 256, 0, stream>>>(
        Abig + 1024, 4096, Sbl, 1024, nullptr, Abig + 3072, 4096, 1024, nullptr);

    // CONTINUOUS: out = (Abig @ Bbig^T) * vnorm[col]   (K=4096 fused)
    gemm_mfma_k<1><<<dim3(32, 8), 256, 0, stream>>>(
        Abig, 4096, Bbig, 4096, out, nullptr, 4096, 4096, vnorm);
}

// Round 9
// 829.220 us; speedup vs baseline: 3.4634x; 1.1347x over previous
//
#include <hip/hip_runtime.h>
#include <math.h>

#ifndef M_PI
#define M_PI 3.14159265358979323846
#endif

typedef __attribute__((ext_vector_type(8))) __bf16 bf16x8;
typedef __attribute__((ext_vector_type(4))) float f32x4;
typedef __attribute__((ext_vector_type(8))) unsigned short ushort8;
typedef __attribute__((ext_vector_type(4))) unsigned short ushort4v;

__device__ __forceinline__ unsigned short f2bf(float x) {
    unsigned int u = __float_as_uint(x);
    unsigned int r = (u + 0x7FFFu + ((u >> 16) & 1u)) >> 16;
    return (unsigned short)r;
}

// ---------------------------------------------------------------------------
// numpy-exact row norms of keys (4096 x 2048), 16 rows/block, 16 thr/row.
// den[r] = nrm + 1e-8f (decision path), vnorm[r] = nrm (continuous colscale)
// ---------------------------------------------------------------------------
__global__ __launch_bounds__(256)
void norm_np_k(const float* __restrict__ keys,
               float* __restrict__ den,
               float* __restrict__ vnorm)
{
#pragma clang fp contract(off)
    const int tid = threadIdx.x;
    const int row_l = tid >> 4;
    const int blk = tid & 15;
    const int row = blockIdx.x * 16 + row_l;
    const float* a = keys + (size_t)row * 2048 + blk * 128;

    float r0 = a[0]*a[0], r1 = a[1]*a[1], r2 = a[2]*a[2], r3 = a[3]*a[3];
    float r4 = a[4]*a[4], r5 = a[5]*a[5], r6 = a[6]*a[6], r7 = a[7]*a[7];
    for (int i = 8; i < 128; i += 8) {
        r0 += a[i+0]*a[i+0]; r1 += a[i+1]*a[i+1];
        r2 += a[i+2]*a[i+2]; r3 += a[i+3]*a[i+3];
        r4 += a[i+4]*a[i+4]; r5 += a[i+5]*a[i+5];
        r6 += a[i+6]*a[i+6]; r7 += a[i+7]*a[i+7];
    }
    float bsum = ((r0 + r1) + (r2 + r3)) + ((r4 + r5) + (r6 + r7));

    __shared__ float bs[16][16];
    bs[row_l][blk] = bsum;
    __syncthreads();
    if (blk == 0) {
        const float* b = bs[row_l];
        float q0 = ((b[0] + b[1]) + (b[2] + b[3])) + ((b[4] + b[5]) + (b[6] + b[7]));
        float q1 = ((b[8] + b[9]) + (b[10] + b[11])) + ((b[12] + b[13]) + (b[14] + b[15]));
        float s = q0 + q1;
        float n = (float)sqrt((double)s);
        den[row] = n + 1e-8f;
        vnorm[row] = n;
    }
}

// ---------------------------------------------------------------------------
// kn[r,d] = keys[r,d] / den[r]  (correctly-rounded f32 div; decision-exact)
// ---------------------------------------------------------------------------
__global__ __launch_bounds__(256)
void kn_k(const float* __restrict__ keys,
          const float* __restrict__ den,
          float* __restrict__ kn)
{
#pragma clang fp contract(off)
    const int idx = (blockIdx.x * 256 + threadIdx.x) * 8;
    const int row = idx >> 11;
    const float d = den[row];
    float4 v0 = *(const float4*)(keys + idx);
    float4 v1 = *(const float4*)(keys + idx + 4);
    v0.x /= d; v0.y /= d; v0.z /= d; v0.w /= d;
    v1.x /= d; v1.y /= d; v1.z /= d; v1.w /= d;
    *(float4*)(kn + idx) = v0;
    *(float4*)(kn + idx + 4) = v1;
}

// ---------------------------------------------------------------------------
// f32 -> bf16 (RNE), 8 elements/thread.
// ---------------------------------------------------------------------------
__global__ __launch_bounds__(256)
void f2bf_k(const float* __restrict__ in, unsigned short* __restrict__ out)
{
    const int i = (blockIdx.x * 256 + threadIdx.x) * 8;
    float4 v0 = *(const float4*)(in + i);
    float4 v1 = *(const float4*)(in + i + 4);
    ushort8 o;
    o[0] = f2bf(v0.x); o[1] = f2bf(v0.y); o[2] = f2bf(v0.z); o[3] = f2bf(v0.w);
    o[4] = f2bf(v1.x); o[5] = f2bf(v1.y); o[6] = f2bf(v1.z); o[7] = f2bf(v1.w);
    *(ushort8*)(out + i) = o;
}

// ---------------------------------------------------------------------------
// Decision-path f32 GEMM (bitwise numpy-f32 chain): C = A(MxK) @ B(NxK)^T.
// Per output element: ONE sequential-k fmaf chain, contract off.
// 128x128 tile, 256 threads, 2x2 blocks of 4x4 per thread (conflict-free:
// b-frag float4 at 16B lane stride = 2 lanes/bank; a-frag broadcast).
// Pipelined: global stage prefetch + ping-pong register fragments.
// blockIdx.z selects (A+z*a_zoff, B0/B1, rv0/rv1, Cb+z*c_zoff).
//   EPI 0: Cf[r,c] = total (f32)
//   EPI 1: Cb[r,c] = bf16( sign(total) * rv[r] )
// ---------------------------------------------------------------------------
template <int EPI>
__global__ __launch_bounds__(256)
void gemm_dec_k(const float* __restrict__ A, int lda, int a_zoff,
                const float* __restrict__ B0, const float* __restrict__ B1,
                int ldb,
                float* __restrict__ Cf, unsigned short* __restrict__ Cb,
                int c_zoff, int ldc, int K,
                const float* __restrict__ rv0, const float* __restrict__ rv1)
{
#pragma clang fp contract(off)
    __shared__ float As[16][132];
    __shared__ float Bs[16][132];

    const int z = blockIdx.z;
    const float* Ap = A + (size_t)z * a_zoff;
    const float* Bp = z ? B1 : B0;
    const float* rvp = z ? rv1 : rv0;
    unsigned short* Cbp = (EPI == 1) ? (Cb + (size_t)z * c_zoff) : nullptr;

    const int tid = threadIdx.x;
    const int tr4 = (tid >> 4) * 4;
    const int tc4 = (tid & 15) * 4;
    const int row0 = blockIdx.y * 128;
    const int col0 = blockIdx.x * 128;
    const int sr = tid >> 1;
    const int sk = (tid & 1) * 8;

    const float* ga = Ap + (size_t)(row0 + sr) * lda + sk;
    const float* gb = Bp + (size_t)(col0 + sr) * ldb + sk;

    float acc[2][2][4][4] = {};
    float sa[8], sb[8];

#define LOADSTAGE(off) do { \
    *(float4*)(sa)     = *(const float4*)(ga + (off)); \
    *(float4*)(sa + 4) = *(const float4*)(ga + (off) + 4); \
    *(float4*)(sb)     = *(const float4*)(gb + (off)); \
    *(float4*)(sb + 4) = *(const float4*)(gb + (off) + 4); \
} while (0)

#define RDFRAG(fa, fb, kk) do { \
    *(float4*)(fa)     = *(const float4*)&As[kk][tr4]; \
    *(float4*)(fa + 4) = *(const float4*)&As[kk][tr4 + 64]; \
    *(float4*)(fb)     = *(const float4*)&Bs[kk][tc4]; \
    *(float4*)(fb + 4) = *(const float4*)&Bs[kk][tc4 + 64]; \
} while (0)

#define FMAS(fa, fb) do { \
    _Pragma("unroll") \
    for (int mb = 0; mb < 2; ++mb) \
        _Pragma("unroll") \
        for (int i = 0; i < 4; ++i) \
            _Pragma("unroll") \
            for (int nb = 0; nb < 2; ++nb) \
                _Pragma("unroll") \
                for (int j = 0; j < 4; ++j) \
                    acc[mb][nb][i][j] = fmaf((fa)[mb*4+i], (fb)[nb*4+j], acc[mb][nb][i][j]); \
} while (0)

    LOADSTAGE(0);

    for (int k0 = 0; k0 < K; k0 += 16) {
        __syncthreads();
        #pragma unroll
        for (int u = 0; u < 8; ++u) {
            As[sk + u][sr] = sa[u];
            Bs[sk + u][sr] = sb[u];
        }
        __syncthreads();
        if (k0 + 16 < K) LOADSTAGE(k0 + 16);

        float fa0[8], fb0[8], fa1[8], fb1[8];
        RDFRAG(fa0, fb0, 0);
        #pragma unroll
        for (int kk = 0; kk < 16; kk += 2) {
            RDFRAG(fa1, fb1, kk + 1);
            FMAS(fa0, fb0);
            if (kk + 2 < 16) RDFRAG(fa0, fb0, kk + 2);
            FMAS(fa1, fb1);
        }
    }

    #pragma unroll
    for (int mb = 0; mb < 2; ++mb) {
        #pragma unroll
        for (int i = 0; i < 4; ++i) {
            const int r = row0 + mb * 64 + tr4 + i;
            if (EPI == 0) {
                #pragma unroll
                for (int nb = 0; nb < 2; ++nb)
                    *(float4*)&Cf[(size_t)r * ldc + col0 + nb * 64 + tc4] =
                        *(const float4*)&acc[mb][nb][i][0];
            } else {
                const float s = rvp[r];
                #pragma unroll
                for (int nb = 0; nb < 2; ++nb) {
                    ushort4v o;
                    #pragma unroll
                    for (int j = 0; j < 4; ++j) {
                        const float t = acc[mb][nb][i][j];
                        o[j] = f2bf((t > 0.0f) ? s : ((t < 0.0f) ? -s : 0.0f));
                    }
                    *(ushort4v*)&Cbp[(size_t)r * ldc + col0 + nb * 64 + tc4] = o;
                }
            }
        }
    }
#undef LOADSTAGE
#undef RDFRAG
#undef FMAS
}

// ---------------------------------------------------------------------------
// Quantize one key row (f32, numpy-exact decisions): nearest centroid
// (first-min ties), residual in place over Y, bf16 y_mse into Bbig[:,0:2048],
// sc = coef * ||res_group||  (continuous; vnorm applied in final colscale).
// ---------------------------------------------------------------------------
__global__ __launch_bounds__(256)
void quant_k(float* __restrict__ Y,
             unsigned short* __restrict__ Bmse,   // ld 4096
             const float* __restrict__ ch,
             const float* __restrict__ cl,
             float* __restrict__ sc_h,
             float* __restrict__ sc_l,
             double coefd)
{
#pragma clang fp contract(off)
    const int row = blockIdx.x;
    const int tid = threadIdx.x;
    const int c0 = tid * 8;
    const float h0 = ch[0], h1 = ch[1], h2 = ch[2], h3 = ch[3];
    const float l0 = cl[0], l1 = cl[1];

    float y[8], res[8];
    ushort8 cb;
    *(float4*)(y)     = *(const float4*)(Y + (size_t)row * 2048 + c0);
    *(float4*)(y + 4) = *(const float4*)(Y + (size_t)row * 2048 + c0 + 4);

    const bool high = (tid < 128);
    float ss = 0.0f;
    #pragma unroll
    for (int j = 0; j < 8; ++j) {
        const float v = y[j];
        float cbest;
        if (high) {
            cbest = h0;
            float bd = fabsf(v - h0), dd;
            dd = fabsf(v - h1); if (dd < bd) { bd = dd; cbest = h1; }
            dd = fabsf(v - h2); if (dd < bd) { bd = dd; cbest = h2; }
            dd = fabsf(v - h3); if (dd < bd) { bd = dd; cbest = h3; }
        } else {
            cbest = (fabsf(v - l1) < fabsf(v - l0)) ? l1 : l0;
        }
        res[j] = v - cbest;
        cb[j] = f2bf(cbest);
        ss += res[j] * res[j];
    }
    *(float4*)(Y + (size_t)row * 2048 + c0)     = *(float4*)(res);
    *(float4*)(Y + (size_t)row * 2048 + c0 + 4) = *(float4*)(res + 4);
    *(ushort8*)(Bmse + (size_t)row * 4096 + c0) = cb;

    __shared__ float sm[256];
    sm[tid] = ss;
    __syncthreads();
    for (int o = 64; o > 0; o >>= 1) {
        if ((tid & 127) < o) sm[tid] += sm[tid + o];
        __syncthreads();
    }
    if (tid == 0)   sc_h[row] = (float)(coefd * sqrt((double)sm[0]));
    if (tid == 128) sc_l[row] = (float)(coefd * sqrt((double)sm[128]));
}

// ---------------------------------------------------------------------------
// Continuous-path bf16 MFMA GEMM: C = A(MxK bf16) @ B(NxK bf16)^T, f32 accum.
// 128x128 tile, 4 waves (2x2), 4x4 16x16x32 fragments per wave.
// blockIdx.z selects (A+z*a_zoff, B0/B1, Cb+z*c_zoff).
//   EPI 1: Cf[r,c] = acc * colscale[c]
//   EPI 2: Cb[r,c] = bf16(acc)
// ---------------------------------------------------------------------------
template <int EPI>
__global__ __launch_bounds__(256)
void gemm_mfma_k(const unsigned short* __restrict__ A, int lda, int a_zoff,
                 const unsigned short* __restrict__ B0,
                 const unsigned short* __restrict__ B1, int ldb,
                 float* __restrict__ Cf, unsigned short* __restrict__ Cb,
                 int c_zoff, int ldc, int K,
                 const float* __restrict__ colscale)
{
    __shared__ unsigned short As[128][40];
    __shared__ unsigned short Bs[128][40];

    const int z = blockIdx.z;
    const unsigned short* Ap = A + (size_t)z * a_zoff;
    const unsigned short* Bp = z ? B1 : B0;
    unsigned short* Cbp = (EPI == 2) ? (Cb + (size_t)z * c_zoff) : nullptr;

    const int tid = threadIdx.x;
    const int lane = tid & 63;
    const int wid = tid >> 6;
    const int wm = wid >> 1;
    const int wn = wid & 1;
    const int row0 = blockIdx.y * 128;
    const int col0 = blockIdx.x * 128;
    const int sr = tid >> 1;
    const int sk = (tid & 1) * 16;
    const int frow = lane & 15;
    const int fk = (lane >> 4) * 8;

    const unsigned short* ga = Ap + (size_t)(row0 + sr) * lda + sk;
    const unsigned short* gb = Bp + (size_t)(col0 + sr) * ldb + sk;

    f32x4 acc[4][4] = {};

    for (int k0 = 0; k0 < K; k0 += 32) {
        ushort8 a0 = *(const ushort8*)(ga + k0);
        ushort8 a1 = *(const ushort8*)(ga + k0 + 8);
        ushort8 b0 = *(const ushort8*)(gb + k0);
        ushort8 b1 = *(const ushort8*)(gb + k0 + 8);
        __syncthreads();
        *(ushort8*)&As[sr][sk]     = a0;
        *(ushort8*)&As[sr][sk + 8] = a1;
        *(ushort8*)&Bs[sr][sk]     = b0;
        *(ushort8*)&Bs[sr][sk + 8] = b1;
        __syncthreads();

        bf16x8 af[4], bfr[4];
        #pragma unroll
        for (int mi = 0; mi < 4; ++mi)
            af[mi] = *(const bf16x8*)&As[wm * 64 + mi * 16 + frow][fk];
        #pragma unroll
        for (int ni = 0; ni < 4; ++ni)
            bfr[ni] = *(const bf16x8*)&Bs[wn * 64 + ni * 16 + frow][fk];
        #pragma unroll
        for (int mi = 0; mi < 4; ++mi)
            #pragma unroll
            for (int ni = 0; ni < 4; ++ni)
                acc[mi][ni] = __builtin_amdgcn_mfma_f32_16x16x32_bf16(
                    af[mi], bfr[ni], acc[mi][ni], 0, 0, 0);
    }

    const int drow = (lane >> 4) * 4;
    const int dcol = lane & 15;
    #pragma unroll
    for (int mi = 0; mi < 4; ++mi) {
        #pragma unroll
        for (int ni = 0; ni < 4; ++ni) {
            const int c = col0 + wn * 64 + ni * 16 + dcol;
            const float cs = (EPI == 1) ? colscale[c] : 0.0f;
            #pragma unroll
            for (int rg = 0; rg < 4; ++rg) {
                const int r = row0 + wm * 64 + mi * 16 + drow + rg;
                const float v = acc[mi][ni][rg];
                if (EPI == 1) Cf[(size_t)r * ldc + c] = v * cs;
                else          Cbp[(size_t)r * ldc + c] = f2bf(v);
            }
        }
    }
}

// ---------------------------------------------------------------------------
// Launch. Workspace (~120.1 MB):
//   kn    @   0M : 4096x2048 f32
//   Y     @  32M : 4096x2048 f32 (y, then residual in place)
//   Bbig  @  64M : 4096x4096 bf16  [ymse | sgn*sc_h | sgn*sc_l]
//   Abig  @  96M : 1024x4096 bf16  [q_rot | z_h | z_l]
//   Qb    @ 104M, Pib @ 108M, Sbh @ 116M, Sbl @ 118M : bf16 inputs
//   den   @ 120M, vnorm +16K, sc_h +32K, sc_l +48K
// ---------------------------------------------------------------------------
extern "C" void kernel_launch(void* const* d_in, const int* in_sizes, int n_in,
                              void* d_out, int out_size, void* d_ws, size_t ws_size,
                              hipStream_t stream)
{
    const float* queries = (const float*)d_in[0];
    const float* keys    = (const float*)d_in[1];
    const float* Pi      = (const float*)d_in[2];
    const float* ch      = (const float*)d_in[3];
    const float* cl      = (const float*)d_in[4];
    const float* S_high  = (const float*)d_in[5];
    const float* S_low   = (const float*)d_in[6];
    float* out = (float*)d_out;

    char* ws = (char*)d_ws;
    float*          kn    = (float*)(ws);
    float*          Y     = (float*)(ws + ((size_t)32 << 20));
    unsigned short* Bbig  = (unsigned short*)(ws + ((size_t)64 << 20));
    unsigned short* Abig  = (unsigned short*)(ws + ((size_t)96 << 20));
    unsigned short* Qb    = (unsigned short*)(ws + ((size_t)104 << 20));
    unsigned short* Pib   = (unsigned short*)(ws + ((size_t)108 << 20));
    unsigned short* Sbh   = (unsigned short*)(ws + ((size_t)116 << 20));
    unsigned short* Sbl   = (unsigned short*)(ws + ((size_t)118 << 20));
    float*          den   = (float*)(ws + ((size_t)120 << 20));
    float*          vnorm = (float*)(ws + ((size_t)120 << 20) + 16384);
    float*          sc_h  = (float*)(ws + ((size_t)120 << 20) + 32768);
    float*          sc_l  = (float*)(ws + ((size_t)120 << 20) + 49152);

    const double coefd = sqrt(M_PI / 2.0) / 1024.0;

    // numpy-exact norms
    norm_np_k<<<256, 256, 0, stream>>>(keys, den, vnorm);

    // decision-exact normalized keys
    kn_k<<<4096, 256, 0, stream>>>(keys, den, kn);

    // bf16 copies for the continuous MFMA path
    f2bf_k<<<1024, 256, 0, stream>>>(queries, Qb);
    f2bf_k<<<2048, 256, 0, stream>>>(Pi, Pib);
    f2bf_k<<<512, 256, 0, stream>>>(S_high, Sbh);
    f2bf_k<<<512, 256, 0, stream>>>(S_low, Sbl);

    // DECISION: Y = kn @ Pi^T  (f32 exact sequential chain)
    gemm_dec_k<0><<<dim3(16, 32, 1), 256, 0, stream>>>(
        kn, 2048, 0, Pi, Pi, 2048, Y, nullptr, 0, 2048, 2048, nullptr, nullptr);

    // DECISION: quantize -> residual in Y, bf16 ymse in Bbig, sc_h/sc_l
    quant_k<<<4096, 256, 0, stream>>>(Y, Bbig, ch, cl, sc_h, sc_l, coefd);

    // DECISION: scaled signs (z=0: high, z=1: low) -> bf16 into Bbig cols 2048+
    gemm_dec_k<1><<<dim3(8, 32, 2), 256, 0, stream>>>(
        Y, 2048, 1024, S_high, S_low, 1024,
        nullptr, Bbig + 2048, 1024, 4096, 1024, sc_h, sc_l);

    // CONTINUOUS (bf16 MFMA): Abig = [q_rot | z_h | z_l]
    gemm_mfma_k<2><<<dim3(16, 8, 1), 256, 0, stream>>>(
        Qb, 2048, 0, Pib, Pib, 2048, nullptr, Abig, 0, 4096, 2048, nullptr);
    gemm_mfma_k<2><<<dim3(8, 8, 2), 256, 0, stream>>>(
        Abig, 4096, 1024, Sbh, Sbl, 1024, nullptr, Abig + 2048, 1024, 4096, 1024, nullptr);

    // CONTINUOUS: out = (Abig @ Bbig^T) * vnorm[col]   (K=4096 fused)
    gemm_mfma_k<1><<<dim3(32, 8, 1), 256, 0, stream>>>(
        Abig, 4096, 0, Bbig, Bbig, 4096, out, nullptr, 0, 4096, 4096, vnorm);
}

// Round 10
// 800.397 us; speedup vs baseline: 3.5881x; 1.0360x over previous
//
#include <hip/hip_runtime.h>
#include <math.h>

#ifndef M_PI
#define M_PI 3.14159265358979323846
#endif

typedef __attribute__((ext_vector_type(8))) __bf16 bf16x8;
typedef __attribute__((ext_vector_type(4))) float f32x4;
typedef __attribute__((ext_vector_type(2))) float f32x2;
typedef __attribute__((ext_vector_type(8))) unsigned short ushort8;
typedef __attribute__((ext_vector_type(4))) unsigned short ushort4v;

__device__ __forceinline__ unsigned short f2bf(float x) {
    unsigned int u = __float_as_uint(x);
    unsigned int r = (u + 0x7FFFu + ((u >> 16) & 1u)) >> 16;
    return (unsigned short)r;
}

// packed f32 FMA: two independent IEEE fmaf lanes per instruction.
// PKFMA_L: d = { fma(a.x,b.x,d.x), fma(a.x,b.y,d.y) }   (broadcast a.lo)
// PKFMA_H: d = { fma(a.y,b.x,d.x), fma(a.y,b.y,d.y) }   (broadcast a.hi)
#define PKFMA_L(d, a, b) \
    asm("v_pk_fma_f32 %0, %1, %2, %0 op_sel:[0,0,0] op_sel_hi:[0,1,1]" \
        : "+v"(d) : "v"(a), "v"(b))
#define PKFMA_H(d, a, b) \
    asm("v_pk_fma_f32 %0, %1, %2, %0 op_sel:[1,0,0] op_sel_hi:[1,1,1]" \
        : "+v"(d) : "v"(a), "v"(b))

// ---------------------------------------------------------------------------
// numpy-exact row norms of keys (4096 x 2048), 16 rows/block, 16 thr/row.
// den[r] = nrm + 1e-8f (decision path), vnorm[r] = nrm (continuous colscale)
// ---------------------------------------------------------------------------
__global__ __launch_bounds__(256)
void norm_np_k(const float* __restrict__ keys,
               float* __restrict__ den,
               float* __restrict__ vnorm)
{
#pragma clang fp contract(off)
    const int tid = threadIdx.x;
    const int row_l = tid >> 4;
    const int blk = tid & 15;
    const int row = blockIdx.x * 16 + row_l;
    const float* a = keys + (size_t)row * 2048 + blk * 128;

    float r0 = a[0]*a[0], r1 = a[1]*a[1], r2 = a[2]*a[2], r3 = a[3]*a[3];
    float r4 = a[4]*a[4], r5 = a[5]*a[5], r6 = a[6]*a[6], r7 = a[7]*a[7];
    for (int i = 8; i < 128; i += 8) {
        r0 += a[i+0]*a[i+0]; r1 += a[i+1]*a[i+1];
        r2 += a[i+2]*a[i+2]; r3 += a[i+3]*a[i+3];
        r4 += a[i+4]*a[i+4]; r5 += a[i+5]*a[i+5];
        r6 += a[i+6]*a[i+6]; r7 += a[i+7]*a[i+7];
    }
    float bsum = ((r0 + r1) + (r2 + r3)) + ((r4 + r5) + (r6 + r7));

    __shared__ float bs[16][16];
    bs[row_l][blk] = bsum;
    __syncthreads();
    if (blk == 0) {
        const float* b = bs[row_l];
        float q0 = ((b[0] + b[1]) + (b[2] + b[3])) + ((b[4] + b[5]) + (b[6] + b[7]));
        float q1 = ((b[8] + b[9]) + (b[10] + b[11])) + ((b[12] + b[13]) + (b[14] + b[15]));
        float s = q0 + q1;
        float n = (float)sqrt((double)s);
        den[row] = n + 1e-8f;
        vnorm[row] = n;
    }
}

// ---------------------------------------------------------------------------
// kn[r,d] = keys[r,d] / den[r]  (correctly-rounded f32 div; decision-exact)
// ---------------------------------------------------------------------------
__global__ __launch_bounds__(256)
void kn_k(const float* __restrict__ keys,
          const float* __restrict__ den,
          float* __restrict__ kn)
{
#pragma clang fp contract(off)
    const int idx = (blockIdx.x * 256 + threadIdx.x) * 8;
    const int row = idx >> 11;
    const float d = den[row];
    float4 v0 = *(const float4*)(keys + idx);
    float4 v1 = *(const float4*)(keys + idx + 4);
    v0.x /= d; v0.y /= d; v0.z /= d; v0.w /= d;
    v1.x /= d; v1.y /= d; v1.z /= d; v1.w /= d;
    *(float4*)(kn + idx) = v0;
    *(float4*)(kn + idx + 4) = v1;
}

// ---------------------------------------------------------------------------
// f32 -> bf16 (RNE), 8 elements/thread.
// ---------------------------------------------------------------------------
__global__ __launch_bounds__(256)
void f2bf_k(const float* __restrict__ in, unsigned short* __restrict__ out)
{
    const int i = (blockIdx.x * 256 + threadIdx.x) * 8;
    float4 v0 = *(const float4*)(in + i);
    float4 v1 = *(const float4*)(in + i + 4);
    ushort8 o;
    o[0] = f2bf(v0.x); o[1] = f2bf(v0.y); o[2] = f2bf(v0.z); o[3] = f2bf(v0.w);
    o[4] = f2bf(v1.x); o[5] = f2bf(v1.y); o[6] = f2bf(v1.z); o[7] = f2bf(v1.w);
    *(ushort8*)(out + i) = o;
}

// ---------------------------------------------------------------------------
// Decision-path f32 GEMM (bitwise numpy-f32 chain): C = A(MxK) @ B(NxK)^T.
// Per output element: ONE sequential fmaf chain (v_pk_fma_f32 = 2 IEEE f32
// FMA lanes/instr; each output's chain order unchanged -> bit-identical).
// 128x128 tile, 256 threads, 8x8/thread. LDS double-buffered (1 barrier per
// 16-k panel), global prefetch issued a full panel early.
//   EPI 0: Cf[r,c] = total (f32)
//   EPI 1: Cb[r,c] = bf16( sign(total) * rv[r] )
// blockIdx.z selects (A+z*a_zoff, B0/B1, rv0/rv1, Cb+z*c_zoff).
// ---------------------------------------------------------------------------
template <int EPI>
__global__ __launch_bounds__(256)
void gemm_dec_k(const float* __restrict__ A, int lda, int a_zoff,
                const float* __restrict__ B0, const float* __restrict__ B1,
                int ldb,
                float* __restrict__ Cf, unsigned short* __restrict__ Cb,
                int c_zoff, int ldc, int K,
                const float* __restrict__ rv0, const float* __restrict__ rv1)
{
#pragma clang fp contract(off)
    __shared__ float As[2][16][132];
    __shared__ float Bs[2][16][132];

    const int z = blockIdx.z;
    const float* Ap = A + (size_t)z * a_zoff;
    const float* Bp = z ? B1 : B0;
    const float* rvp = z ? rv1 : rv0;
    unsigned short* Cbp = (EPI == 1) ? (Cb + (size_t)z * c_zoff) : nullptr;

    const int tid = threadIdx.x;
    const int tr4 = (tid >> 4) * 4;
    const int tc4 = (tid & 15) * 4;
    const int row0 = blockIdx.y * 128;
    const int col0 = blockIdx.x * 128;
    const int sr = tid >> 1;
    const int sk = (tid & 1) * 8;

    const float* ga = Ap + (size_t)(row0 + sr) * lda + sk;
    const float* gb = Bp + (size_t)(col0 + sr) * ldb + sk;

    f32x2 acc[8][4] = {};
    float sa[8], sb[8];

#define LOADSTAGE(off) do { \
    *(float4*)(sa)     = *(const float4*)(ga + (off)); \
    *(float4*)(sa + 4) = *(const float4*)(ga + (off) + 4); \
    *(float4*)(sb)     = *(const float4*)(gb + (off)); \
    *(float4*)(sb + 4) = *(const float4*)(gb + (off) + 4); \
} while (0)

#define STORESTAGE(buf) do { \
    _Pragma("unroll") \
    for (int u = 0; u < 8; ++u) { \
        As[buf][sk + u][sr] = sa[u]; \
        Bs[buf][sk + u][sr] = sb[u]; \
    } \
} while (0)

#define RDFRAG(fa, fb, kk, buf) do { \
    float4 va0 = *(const float4*)&As[buf][kk][tr4]; \
    float4 va1 = *(const float4*)&As[buf][kk][tr4 + 64]; \
    float4 vb0 = *(const float4*)&Bs[buf][kk][tc4]; \
    float4 vb1 = *(const float4*)&Bs[buf][kk][tc4 + 64]; \
    (fa)[0] = (f32x2){va0.x, va0.y}; (fa)[1] = (f32x2){va0.z, va0.w}; \
    (fa)[2] = (f32x2){va1.x, va1.y}; (fa)[3] = (f32x2){va1.z, va1.w}; \
    (fb)[0] = (f32x2){vb0.x, vb0.y}; (fb)[1] = (f32x2){vb0.z, vb0.w}; \
    (fb)[2] = (f32x2){vb1.x, vb1.y}; (fb)[3] = (f32x2){vb1.z, vb1.w}; \
} while (0)

#define FMAS(fa, fb) do { \
    _Pragma("unroll") \
    for (int p = 0; p < 4; ++p) { \
        _Pragma("unroll") \
        for (int q = 0; q < 4; ++q) { \
            PKFMA_L(acc[2*p][q],   (fa)[p], (fb)[q]); \
            PKFMA_H(acc[2*p+1][q], (fa)[p], (fb)[q]); \
        } \
    } \
} while (0)

    LOADSTAGE(0);
    STORESTAGE(0);
    __syncthreads();
    int cur = 0;

    for (int k0 = 0; k0 < K; k0 += 16) {
        const bool more = (k0 + 16 < K);
        if (more) LOADSTAGE(k0 + 16);

        f32x2 fa0[4], fb0[4], fa1[4], fb1[4];
        RDFRAG(fa0, fb0, 0, cur);
        #pragma unroll
        for (int kk = 0; kk < 16; kk += 2) {
            RDFRAG(fa1, fb1, kk + 1, cur);
            FMAS(fa0, fb0);
            if (kk + 2 < 16) RDFRAG(fa0, fb0, kk + 2, cur);
            FMAS(fa1, fb1);
        }

        if (more) STORESTAGE(cur ^ 1);
        __syncthreads();
        cur ^= 1;
    }

    // rows: ai<4 -> row0+tr4+ai ; ai>=4 -> row0+64+tr4+(ai-4)
    // cols: pair q -> (q<2 ? col0+tc4+2q : col0+64+tc4+2(q-2))
    #pragma unroll
    for (int ai = 0; ai < 8; ++ai) {
        const int r = row0 + ((ai < 4) ? (tr4 + ai) : (64 + tr4 + ai - 4));
        if (EPI == 0) {
            float4 lo4 = {acc[ai][0].x, acc[ai][0].y, acc[ai][1].x, acc[ai][1].y};
            float4 hi4 = {acc[ai][2].x, acc[ai][2].y, acc[ai][3].x, acc[ai][3].y};
            *(float4*)&Cf[(size_t)r * ldc + col0 + tc4]      = lo4;
            *(float4*)&Cf[(size_t)r * ldc + col0 + 64 + tc4] = hi4;
        } else {
            const float s = rvp[r];
            float v[8] = {acc[ai][0].x, acc[ai][0].y, acc[ai][1].x, acc[ai][1].y,
                          acc[ai][2].x, acc[ai][2].y, acc[ai][3].x, acc[ai][3].y};
            ushort4v o0, o1;
            #pragma unroll
            for (int j = 0; j < 4; ++j) {
                const float t0 = v[j];
                o0[j] = f2bf((t0 > 0.0f) ? s : ((t0 < 0.0f) ? -s : 0.0f));
                const float t1 = v[4 + j];
                o1[j] = f2bf((t1 > 0.0f) ? s : ((t1 < 0.0f) ? -s : 0.0f));
            }
            *(ushort4v*)&Cbp[(size_t)r * ldc + col0 + tc4]      = o0;
            *(ushort4v*)&Cbp[(size_t)r * ldc + col0 + 64 + tc4] = o1;
        }
    }
#undef LOADSTAGE
#undef STORESTAGE
#undef RDFRAG
#undef FMAS
}

// ---------------------------------------------------------------------------
// Quantize one key row (f32, numpy-exact decisions): nearest centroid
// (first-min ties), residual in place over Y, bf16 y_mse into Bbig[:,0:2048],
// sc = coef * ||res_group||  (continuous; vnorm applied in final colscale).
// ---------------------------------------------------------------------------
__global__ __launch_bounds__(256)
void quant_k(float* __restrict__ Y,
             unsigned short* __restrict__ Bmse,   // ld 4096
             const float* __restrict__ ch,
             const float* __restrict__ cl,
             float* __restrict__ sc_h,
             float* __restrict__ sc_l,
             double coefd)
{
#pragma clang fp contract(off)
    const int row = blockIdx.x;
    const int tid = threadIdx.x;
    const int c0 = tid * 8;
    const float h0 = ch[0], h1 = ch[1], h2 = ch[2], h3 = ch[3];
    const float l0 = cl[0], l1 = cl[1];

    float y[8], res[8];
    ushort8 cb;
    *(float4*)(y)     = *(const float4*)(Y + (size_t)row * 2048 + c0);
    *(float4*)(y + 4) = *(const float4*)(Y + (size_t)row * 2048 + c0 + 4);

    const bool high = (tid < 128);
    float ss = 0.0f;
    #pragma unroll
    for (int j = 0; j < 8; ++j) {
        const float v = y[j];
        float cbest;
        if (high) {
            cbest = h0;
            float bd = fabsf(v - h0), dd;
            dd = fabsf(v - h1); if (dd < bd) { bd = dd; cbest = h1; }
            dd = fabsf(v - h2); if (dd < bd) { bd = dd; cbest = h2; }
            dd = fabsf(v - h3); if (dd < bd) { bd = dd; cbest = h3; }
        } else {
            cbest = (fabsf(v - l1) < fabsf(v - l0)) ? l1 : l0;
        }
        res[j] = v - cbest;
        cb[j] = f2bf(cbest);
        ss += res[j] * res[j];
    }
    *(float4*)(Y + (size_t)row * 2048 + c0)     = *(float4*)(res);
    *(float4*)(Y + (size_t)row * 2048 + c0 + 4) = *(float4*)(res + 4);
    *(ushort8*)(Bmse + (size_t)row * 4096 + c0) = cb;

    __shared__ float sm[256];
    sm[tid] = ss;
    __syncthreads();
    for (int o = 64; o > 0; o >>= 1) {
        if ((tid & 127) < o) sm[tid] += sm[tid + o];
        __syncthreads();
    }
    if (tid == 0)   sc_h[row] = (float)(coefd * sqrt((double)sm[0]));
    if (tid == 128) sc_l[row] = (float)(coefd * sqrt((double)sm[128]));
}

// ---------------------------------------------------------------------------
// Continuous-path bf16 MFMA GEMM: C = A(MxK bf16) @ B(NxK bf16)^T, f32 accum.
// 128x128 tile, 4 waves (2x2), 4x4 16x16x32 fragments per wave.
// blockIdx.z selects (A+z*a_zoff, B0/B1, Cb+z*c_zoff).
//   EPI 1: Cf[r,c] = acc * colscale[c]
//   EPI 2: Cb[r,c] = bf16(acc)
// ---------------------------------------------------------------------------
template <int EPI>
__global__ __launch_bounds__(256)
void gemm_mfma_k(const unsigned short* __restrict__ A, int lda, int a_zoff,
                 const unsigned short* __restrict__ B0,
                 const unsigned short* __restrict__ B1, int ldb,
                 float* __restrict__ Cf, unsigned short* __restrict__ Cb,
                 int c_zoff, int ldc, int K,
                 const float* __restrict__ colscale)
{
    __shared__ unsigned short As[128][40];
    __shared__ unsigned short Bs[128][40];

    const int z = blockIdx.z;
    const unsigned short* Ap = A + (size_t)z * a_zoff;
    const unsigned short* Bp = z ? B1 : B0;
    unsigned short* Cbp = (EPI == 2) ? (Cb + (size_t)z * c_zoff) : nullptr;

    const int tid = threadIdx.x;
    const int lane = tid & 63;
    const int wid = tid >> 6;
    const int wm = wid >> 1;
    const int wn = wid & 1;
    const int row0 = blockIdx.y * 128;
    const int col0 = blockIdx.x * 128;
    const int sr = tid >> 1;
    const int sk = (tid & 1) * 16;
    const int frow = lane & 15;
    const int fk = (lane >> 4) * 8;

    const unsigned short* ga = Ap + (size_t)(row0 + sr) * lda + sk;
    const unsigned short* gb = Bp + (size_t)(col0 + sr) * ldb + sk;

    f32x4 acc[4][4] = {};

    for (int k0 = 0; k0 < K; k0 += 32) {
        ushort8 a0 = *(const ushort8*)(ga + k0);
        ushort8 a1 = *(const ushort8*)(ga + k0 + 8);
        ushort8 b0 = *(const ushort8*)(gb + k0);
        ushort8 b1 = *(const ushort8*)(gb + k0 + 8);
        __syncthreads();
        *(ushort8*)&As[sr][sk]     = a0;
        *(ushort8*)&As[sr][sk + 8] = a1;
        *(ushort8*)&Bs[sr][sk]     = b0;
        *(ushort8*)&Bs[sr][sk + 8] = b1;
        __syncthreads();

        bf16x8 af[4], bfr[4];
        #pragma unroll
        for (int mi = 0; mi < 4; ++mi)
            af[mi] = *(const bf16x8*)&As[wm * 64 + mi * 16 + frow][fk];
        #pragma unroll
        for (int ni = 0; ni < 4; ++ni)
            bfr[ni] = *(const bf16x8*)&Bs[wn * 64 + ni * 16 + frow][fk];
        #pragma unroll
        for (int mi = 0; mi < 4; ++mi)
            #pragma unroll
            for (int ni = 0; ni < 4; ++ni)
                acc[mi][ni] = __builtin_amdgcn_mfma_f32_16x16x32_bf16(
                    af[mi], bfr[ni], acc[mi][ni], 0, 0, 0);
    }

    const int drow = (lane >> 4) * 4;
    const int dcol = lane & 15;
    #pragma unroll
    for (int mi = 0; mi < 4; ++mi) {
        #pragma unroll
        for (int ni = 0; ni < 4; ++ni) {
            const int c = col0 + wn * 64 + ni * 16 + dcol;
            const float cs = (EPI == 1) ? colscale[c] : 0.0f;
            #pragma unroll
            for (int rg = 0; rg < 4; ++rg) {
                const int r = row0 + wm * 64 + mi * 16 + drow + rg;
                const float v = acc[mi][ni][rg];
                if (EPI == 1) Cf[(size_t)r * ldc + c] = v * cs;
                else          Cbp[(size_t)r * ldc + c] = f2bf(v);
            }
        }
    }
}

// ---------------------------------------------------------------------------
// Launch. Workspace (~120.1 MB):
//   kn    @   0M : 4096x2048 f32
//   Y     @  32M : 4096x2048 f32 (y, then residual in place)
//   Bbig  @  64M : 4096x4096 bf16  [ymse | sgn*sc_h | sgn*sc_l]
//   Abig  @  96M : 1024x4096 bf16  [q_rot | z_h | z_l]
//   Qb    @ 104M, Pib @ 108M, Sbh @ 116M, Sbl @ 118M : bf16 inputs
//   den   @ 120M, vnorm +16K, sc_h +32K, sc_l +48K
// ---------------------------------------------------------------------------
extern "C" void kernel_launch(void* const* d_in, const int* in_sizes, int n_in,
                              void* d_out, int out_size, void* d_ws, size_t ws_size,
                              hipStream_t stream)
{
    const float* queries = (const float*)d_in[0];
    const float* keys    = (const float*)d_in[1];
    const float* Pi      = (const float*)d_in[2];
    const float* ch      = (const float*)d_in[3];
    const float* cl      = (const float*)d_in[4];
    const float* S_high  = (const float*)d_in[5];
    const float* S_low   = (const float*)d_in[6];
    float* out = (float*)d_out;

    char* ws = (char*)d_ws;
    float*          kn    = (float*)(ws);
    float*          Y     = (float*)(ws + ((size_t)32 << 20));
    unsigned short* Bbig  = (unsigned short*)(ws + ((size_t)64 << 20));
    unsigned short* Abig  = (unsigned short*)(ws + ((size_t)96 << 20));
    unsigned short* Qb    = (unsigned short*)(ws + ((size_t)104 << 20));
    unsigned short* Pib   = (unsigned short*)(ws + ((size_t)108 << 20));
    unsigned short* Sbh   = (unsigned short*)(ws + ((size_t)116 << 20));
    unsigned short* Sbl   = (unsigned short*)(ws + ((size_t)118 << 20));
    float*          den   = (float*)(ws + ((size_t)120 << 20));
    float*          vnorm = (float*)(ws + ((size_t)120 << 20) + 16384);
    float*          sc_h  = (float*)(ws + ((size_t)120 << 20) + 32768);
    float*          sc_l  = (float*)(ws + ((size_t)120 << 20) + 49152);

    const double coefd = sqrt(M_PI / 2.0) / 1024.0;

    // numpy-exact norms
    norm_np_k<<<256, 256, 0, stream>>>(keys, den, vnorm);

    // decision-exact normalized keys
    kn_k<<<4096, 256, 0, stream>>>(keys, den, kn);

    // bf16 copies for the continuous MFMA path
    f2bf_k<<<1024, 256, 0, stream>>>(queries, Qb);
    f2bf_k<<<2048, 256, 0, stream>>>(Pi, Pib);
    f2bf_k<<<512, 256, 0, stream>>>(S_high, Sbh);
    f2bf_k<<<512, 256, 0, stream>>>(S_low, Sbl);

    // DECISION: Y = kn @ Pi^T  (f32 exact sequential chain, pk_fma)
    gemm_dec_k<0><<<dim3(16, 32, 1), 256, 0, stream>>>(
        kn, 2048, 0, Pi, Pi, 2048, Y, nullptr, 0, 2048, 2048, nullptr, nullptr);

    // DECISION: quantize -> residual in Y, bf16 ymse in Bbig, sc_h/sc_l
    quant_k<<<4096, 256, 0, stream>>>(Y, Bbig, ch, cl, sc_h, sc_l, coefd);

    // DECISION: scaled signs (z=0: high, z=1: low) -> bf16 into Bbig cols 2048+
    gemm_dec_k<1><<<dim3(8, 32, 2), 256, 0, stream>>>(
        Y, 2048, 1024, S_high, S_low, 1024,
        nullptr, Bbig + 2048, 1024, 4096, 1024, sc_h, sc_l);

    // CONTINUOUS (bf16 MFMA): Abig = [q_rot | z_h | z_l]
    gemm_mfma_k<2><<<dim3(16, 8, 1), 256, 0, stream>>>(
        Qb, 2048, 0, Pib, Pib, 2048, nullptr, Abig, 0, 4096, 2048, nullptr);
    gemm_mfma_k<2><<<dim3(8, 8, 2), 256, 0, stream>>>(
        Abig, 4096, 1024, Sbh, Sbl, 1024, nullptr, Abig + 2048, 1024, 4096, 1024, nullptr);

    // CONTINUOUS: out = (Abig @ Bbig^T) * vnorm[col]   (K=4096 fused)
    gemm_mfma_k<1><<<dim3(32, 8, 1), 256, 0, stream>>>(
        Abig, 4096, 0, Bbig, Bbig, 4096, out, nullptr, 0, 4096, 4096, vnorm);
}

// Round 11
// 800.307 us; speedup vs baseline: 3.5885x; 1.0001x over previous
//
#include <hip/hip_runtime.h>
#include <math.h>

#ifndef M_PI
#define M_PI 3.14159265358979323846
#endif

typedef __attribute__((ext_vector_type(8))) __bf16 bf16x8;
typedef __attribute__((ext_vector_type(4))) float f32x4;
typedef __attribute__((ext_vector_type(2))) float f32x2;
typedef __attribute__((ext_vector_type(8))) unsigned short ushort8;
typedef __attribute__((ext_vector_type(4))) unsigned short ushort4v;

__device__ __forceinline__ unsigned short f2bf(float x) {
    unsigned int u = __float_as_uint(x);
    unsigned int r = (u + 0x7FFFu + ((u >> 16) & 1u)) >> 16;
    return (unsigned short)r;
}

// packed f32 FMA: two independent IEEE fmaf lanes per instruction.
// PKFMA_L: d = { fma(a.x,b.x,d.x), fma(a.x,b.y,d.y) }   (broadcast a.lo)
// PKFMA_H: d = { fma(a.y,b.x,d.x), fma(a.y,b.y,d.y) }   (broadcast a.hi)
#define PKFMA_L(d, a, b) \
    asm("v_pk_fma_f32 %0, %1, %2, %0 op_sel:[0,0,0] op_sel_hi:[0,1,1]" \
        : "+v"(d) : "v"(a), "v"(b))
#define PKFMA_H(d, a, b) \
    asm("v_pk_fma_f32 %0, %1, %2, %0 op_sel:[1,0,0] op_sel_hi:[1,1,1]" \
        : "+v"(d) : "v"(a), "v"(b))

// ---------------------------------------------------------------------------
// numpy-exact row norms of keys (4096 x 2048), 16 rows/block, 16 thr/row.
// den[r] = nrm + 1e-8f (decision path), vnorm[r] = nrm (continuous colscale)
// ---------------------------------------------------------------------------
__global__ __launch_bounds__(256)
void norm_np_k(const float* __restrict__ keys,
               float* __restrict__ den,
               float* __restrict__ vnorm)
{
#pragma clang fp contract(off)
    const int tid = threadIdx.x;
    const int row_l = tid >> 4;
    const int blk = tid & 15;
    const int row = blockIdx.x * 16 + row_l;
    const float* a = keys + (size_t)row * 2048 + blk * 128;

    float r0 = a[0]*a[0], r1 = a[1]*a[1], r2 = a[2]*a[2], r3 = a[3]*a[3];
    float r4 = a[4]*a[4], r5 = a[5]*a[5], r6 = a[6]*a[6], r7 = a[7]*a[7];
    for (int i = 8; i < 128; i += 8) {
        r0 += a[i+0]*a[i+0]; r1 += a[i+1]*a[i+1];
        r2 += a[i+2]*a[i+2]; r3 += a[i+3]*a[i+3];
        r4 += a[i+4]*a[i+4]; r5 += a[i+5]*a[i+5];
        r6 += a[i+6]*a[i+6]; r7 += a[i+7]*a[i+7];
    }
    float bsum = ((r0 + r1) + (r2 + r3)) + ((r4 + r5) + (r6 + r7));

    __shared__ float bs[16][16];
    bs[row_l][blk] = bsum;
    __syncthreads();
    if (blk == 0) {
        const float* b = bs[row_l];
        float q0 = ((b[0] + b[1]) + (b[2] + b[3])) + ((b[4] + b[5]) + (b[6] + b[7]));
        float q1 = ((b[8] + b[9]) + (b[10] + b[11])) + ((b[12] + b[13]) + (b[14] + b[15]));
        float s = q0 + q1;
        float n = (float)sqrt((double)s);
        den[row] = n + 1e-8f;
        vnorm[row] = n;
    }
}

// ---------------------------------------------------------------------------
// kn[r,d] = keys[r,d] / den[r]  (correctly-rounded f32 div; decision-exact)
// ---------------------------------------------------------------------------
__global__ __launch_bounds__(256)
void kn_k(const float* __restrict__ keys,
          const float* __restrict__ den,
          float* __restrict__ kn)
{
#pragma clang fp contract(off)
    const int idx = (blockIdx.x * 256 + threadIdx.x) * 8;
    const int row = idx >> 11;
    const float d = den[row];
    float4 v0 = *(const float4*)(keys + idx);
    float4 v1 = *(const float4*)(keys + idx + 4);
    v0.x /= d; v0.y /= d; v0.z /= d; v0.w /= d;
    v1.x /= d; v1.y /= d; v1.z /= d; v1.w /= d;
    *(float4*)(kn + idx) = v0;
    *(float4*)(kn + idx + 4) = v1;
}

// ---------------------------------------------------------------------------
// f32 -> bf16 (RNE), 8 elements/thread.
// ---------------------------------------------------------------------------
__global__ __launch_bounds__(256)
void f2bf_k(const float* __restrict__ in, unsigned short* __restrict__ out)
{
    const int i = (blockIdx.x * 256 + threadIdx.x) * 8;
    float4 v0 = *(const float4*)(in + i);
    float4 v1 = *(const float4*)(in + i + 4);
    ushort8 o;
    o[0] = f2bf(v0.x); o[1] = f2bf(v0.y); o[2] = f2bf(v0.z); o[3] = f2bf(v0.w);
    o[4] = f2bf(v1.x); o[5] = f2bf(v1.y); o[6] = f2bf(v1.z); o[7] = f2bf(v1.w);
    *(ushort8*)(out + i) = o;
}

// ---------------------------------------------------------------------------
// Decision-path f32 GEMM (bitwise numpy-f32 chain): C = A(MxK) @ B(NxK)^T.
// Per output element: ONE sequential fmaf chain (v_pk_fma_f32 = 2 IEEE f32
// FMA lanes/instr; each output's chain order unchanged -> bit-identical).
// 128x128 tile, 256 threads, 8x8/thread. LDS double-buffered.
// __launch_bounds__(256, 2): we run 2 blocks/CU (8 waves/CU = 2 waves/EU);
// declaring it unlocks the VGPR budget so the 32 f32x2 accumulators live in
// ARCH VGPRs. With the default bound the compiler parked acc in AGPRs and
// wrapped every inline-asm pk_fma ("v" constraints) in v_accvgpr_read/write
// pairs -> ~40% of all SIMD cycles were accvgpr traffic (r10 profile: FMA
// issue 26% of cycles, VALUBusy 66%, VGPR_Count 64).
//   EPI 0: Cf[r,c] = total (f32)
//   EPI 1: Cb[r,c] = bf16( sign(total) * rv[r] )
// blockIdx.z selects (A+z*a_zoff, B0/B1, rv0/rv1, Cb+z*c_zoff).
// ---------------------------------------------------------------------------
template <int EPI>
__global__ __launch_bounds__(256, 2)
void gemm_dec_k(const float* __restrict__ A, int lda, int a_zoff,
                const float* __restrict__ B0, const float* __restrict__ B1,
                int ldb,
                float* __restrict__ Cf, unsigned short* __restrict__ Cb,
                int c_zoff, int ldc, int K,
                const float* __restrict__ rv0, const float* __restrict__ rv1)
{
#pragma clang fp contract(off)
    __shared__ float As[2][16][132];
    __shared__ float Bs[2][16][132];

    const int z = blockIdx.z;
    const float* Ap = A + (size_t)z * a_zoff;
    const float* Bp = z ? B1 : B0;
    const float* rvp = z ? rv1 : rv0;
    unsigned short* Cbp = (EPI == 1) ? (Cb + (size_t)z * c_zoff) : nullptr;

    const int tid = threadIdx.x;
    const int tr4 = (tid >> 4) * 4;
    const int tc4 = (tid & 15) * 4;
    const int row0 = blockIdx.y * 128;
    const int col0 = blockIdx.x * 128;
    const int sr = tid >> 1;
    const int sk = (tid & 1) * 8;

    const float* ga = Ap + (size_t)(row0 + sr) * lda + sk;
    const float* gb = Bp + (size_t)(col0 + sr) * ldb + sk;

    f32x2 acc[8][4] = {};
    float sa[8], sb[8];

#define LOADSTAGE(off) do { \
    *(float4*)(sa)     = *(const float4*)(ga + (off)); \
    *(float4*)(sa + 4) = *(const float4*)(ga + (off) + 4); \
    *(float4*)(sb)     = *(const float4*)(gb + (off)); \
    *(float4*)(sb + 4) = *(const float4*)(gb + (off) + 4); \
} while (0)

#define STORESTAGE(buf) do { \
    _Pragma("unroll") \
    for (int u = 0; u < 8; ++u) { \
        As[buf][sk + u][sr] = sa[u]; \
        Bs[buf][sk + u][sr] = sb[u]; \
    } \
} while (0)

#define RDFRAG(fa, fb, kk, buf) do { \
    float4 va0 = *(const float4*)&As[buf][kk][tr4]; \
    float4 va1 = *(const float4*)&As[buf][kk][tr4 + 64]; \
    float4 vb0 = *(const float4*)&Bs[buf][kk][tc4]; \
    float4 vb1 = *(const float4*)&Bs[buf][kk][tc4 + 64]; \
    (fa)[0] = (f32x2){va0.x, va0.y}; (fa)[1] = (f32x2){va0.z, va0.w}; \
    (fa)[2] = (f32x2){va1.x, va1.y}; (fa)[3] = (f32x2){va1.z, va1.w}; \
    (fb)[0] = (f32x2){vb0.x, vb0.y}; (fb)[1] = (f32x2){vb0.z, vb0.w}; \
    (fb)[2] = (f32x2){vb1.x, vb1.y}; (fb)[3] = (f32x2){vb1.z, vb1.w}; \
} while (0)

#define FMAS(fa, fb) do { \
    _Pragma("unroll") \
    for (int p = 0; p < 4; ++p) { \
        _Pragma("unroll") \
        for (int q = 0; q < 4; ++q) { \
            PKFMA_L(acc[2*p][q],   (fa)[p], (fb)[q]); \
            PKFMA_H(acc[2*p+1][q], (fa)[p], (fb)[q]); \
        } \
    } \
} while (0)

    LOADSTAGE(0);
    STORESTAGE(0);
    __syncthreads();
    int cur = 0;

    for (int k0 = 0; k0 < K; k0 += 16) {
        const bool more = (k0 + 16 < K);
        if (more) LOADSTAGE(k0 + 16);

        f32x2 fa0[4], fb0[4], fa1[4], fb1[4];
        RDFRAG(fa0, fb0, 0, cur);
        #pragma unroll
        for (int kk = 0; kk < 16; kk += 2) {
            RDFRAG(fa1, fb1, kk + 1, cur);
            FMAS(fa0, fb0);
            if (kk + 2 < 16) RDFRAG(fa0, fb0, kk + 2, cur);
            FMAS(fa1, fb1);
        }

        if (more) STORESTAGE(cur ^ 1);
        __syncthreads();
        cur ^= 1;
    }

    // rows: ai<4 -> row0+tr4+ai ; ai>=4 -> row0+64+tr4+(ai-4)
    #pragma unroll
    for (int ai = 0; ai < 8; ++ai) {
        const int r = row0 + ((ai < 4) ? (tr4 + ai) : (64 + tr4 + ai - 4));
        if (EPI == 0) {
            float4 lo4 = {acc[ai][0].x, acc[ai][0].y, acc[ai][1].x, acc[ai][1].y};
            float4 hi4 = {acc[ai][2].x, acc[ai][2].y, acc[ai][3].x, acc[ai][3].y};
            *(float4*)&Cf[(size_t)r * ldc + col0 + tc4]      = lo4;
            *(float4*)&Cf[(size_t)r * ldc + col0 + 64 + tc4] = hi4;
        } else {
            const float s = rvp[r];
            float v[8] = {acc[ai][0].x, acc[ai][0].y, acc[ai][1].x, acc[ai][1].y,
                          acc[ai][2].x, acc[ai][2].y, acc[ai][3].x, acc[ai][3].y};
            ushort4v o0, o1;
            #pragma unroll
            for (int j = 0; j < 4; ++j) {
                const float t0 = v[j];
                o0[j] = f2bf((t0 > 0.0f) ? s : ((t0 < 0.0f) ? -s : 0.0f));
                const float t1 = v[4 + j];
                o1[j] = f2bf((t1 > 0.0f) ? s : ((t1 < 0.0f) ? -s : 0.0f));
            }
            *(ushort4v*)&Cbp[(size_t)r * ldc + col0 + tc4]      = o0;
            *(ushort4v*)&Cbp[(size_t)r * ldc + col0 + 64 + tc4] = o1;
        }
    }
#undef LOADSTAGE
#undef STORESTAGE
#undef RDFRAG
#undef FMAS
}

// ---------------------------------------------------------------------------
// Quantize one key row (f32, numpy-exact decisions): nearest centroid
// (first-min ties), residual in place over Y, bf16 y_mse into Bbig[:,0:2048],
// sc = coef * ||res_group||  (continuous; vnorm applied in final colscale).
// ---------------------------------------------------------------------------
__global__ __launch_bounds__(256)
void quant_k(float* __restrict__ Y,
             unsigned short* __restrict__ Bmse,   // ld 4096
             const float* __restrict__ ch,
             const float* __restrict__ cl,
             float* __restrict__ sc_h,
             float* __restrict__ sc_l,
             double coefd)
{
#pragma clang fp contract(off)
    const int row = blockIdx.x;
    const int tid = threadIdx.x;
    const int c0 = tid * 8;
    const float h0 = ch[0], h1 = ch[1], h2 = ch[2], h3 = ch[3];
    const float l0 = cl[0], l1 = cl[1];

    float y[8], res[8];
    ushort8 cb;
    *(float4*)(y)     = *(const float4*)(Y + (size_t)row * 2048 + c0);
    *(float4*)(y + 4) = *(const float4*)(Y + (size_t)row * 2048 + c0 + 4);

    const bool high = (tid < 128);
    float ss = 0.0f;
    #pragma unroll
    for (int j = 0; j < 8; ++j) {
        const float v = y[j];
        float cbest;
        if (high) {
            cbest = h0;
            float bd = fabsf(v - h0), dd;
            dd = fabsf(v - h1); if (dd < bd) { bd = dd; cbest = h1; }
            dd = fabsf(v - h2); if (dd < bd) { bd = dd; cbest = h2; }
            dd = fabsf(v - h3); if (dd < bd) { bd = dd; cbest = h3; }
        } else {
            cbest = (fabsf(v - l1) < fabsf(v - l0)) ? l1 : l0;
        }
        res[j] = v - cbest;
        cb[j] = f2bf(cbest);
        ss += res[j] * res[j];
    }
    *(float4*)(Y + (size_t)row * 2048 + c0)     = *(float4*)(res);
    *(float4*)(Y + (size_t)row * 2048 + c0 + 4) = *(float4*)(res + 4);
    *(ushort8*)(Bmse + (size_t)row * 4096 + c0) = cb;

    __shared__ float sm[256];
    sm[tid] = ss;
    __syncthreads();
    for (int o = 64; o > 0; o >>= 1) {
        if ((tid & 127) < o) sm[tid] += sm[tid + o];
        __syncthreads();
    }
    if (tid == 0)   sc_h[row] = (float)(coefd * sqrt((double)sm[0]));
    if (tid == 128) sc_l[row] = (float)(coefd * sqrt((double)sm[128]));
}

// ---------------------------------------------------------------------------
// Continuous-path bf16 MFMA GEMM: C = A(MxK bf16) @ B(NxK bf16)^T, f32 accum.
// 128x128 tile, 4 waves (2x2), 4x4 16x16x32 fragments per wave.
// blockIdx.z selects (A+z*a_zoff, B0/B1, Cb+z*c_zoff).
//   EPI 1: Cf[r,c] = acc * colscale[c]
//   EPI 2: Cb[r,c] = bf16(acc)
// ---------------------------------------------------------------------------
template <int EPI>
__global__ __launch_bounds__(256)
void gemm_mfma_k(const unsigned short* __restrict__ A, int lda, int a_zoff,
                 const unsigned short* __restrict__ B0,
                 const unsigned short* __restrict__ B1, int ldb,
                 float* __restrict__ Cf, unsigned short* __restrict__ Cb,
                 int c_zoff, int ldc, int K,
                 const float* __restrict__ colscale)
{
    __shared__ unsigned short As[128][40];
    __shared__ unsigned short Bs[128][40];

    const int z = blockIdx.z;
    const unsigned short* Ap = A + (size_t)z * a_zoff;
    const unsigned short* Bp = z ? B1 : B0;
    unsigned short* Cbp = (EPI == 2) ? (Cb + (size_t)z * c_zoff) : nullptr;

    const int tid = threadIdx.x;
    const int lane = tid & 63;
    const int wid = tid >> 6;
    const int wm = wid >> 1;
    const int wn = wid & 1;
    const int row0 = blockIdx.y * 128;
    const int col0 = blockIdx.x * 128;
    const int sr = tid >> 1;
    const int sk = (tid & 1) * 16;
    const int frow = lane & 15;
    const int fk = (lane >> 4) * 8;

    const unsigned short* ga = Ap + (size_t)(row0 + sr) * lda + sk;
    const unsigned short* gb = Bp + (size_t)(col0 + sr) * ldb + sk;

    f32x4 acc[4][4] = {};

    for (int k0 = 0; k0 < K; k0 += 32) {
        ushort8 a0 = *(const ushort8*)(ga + k0);
        ushort8 a1 = *(const ushort8*)(ga + k0 + 8);
        ushort8 b0 = *(const ushort8*)(gb + k0);
        ushort8 b1 = *(const ushort8*)(gb + k0 + 8);
        __syncthreads();
        *(ushort8*)&As[sr][sk]     = a0;
        *(ushort8*)&As[sr][sk + 8] = a1;
        *(ushort8*)&Bs[sr][sk]     = b0;
        *(ushort8*)&Bs[sr][sk + 8] = b1;
        __syncthreads();

        bf16x8 af[4], bfr[4];
        #pragma unroll
        for (int mi = 0; mi < 4; ++mi)
            af[mi] = *(const bf16x8*)&As[wm * 64 + mi * 16 + frow][fk];
        #pragma unroll
        for (int ni = 0; ni < 4; ++ni)
            bfr[ni] = *(const bf16x8*)&Bs[wn * 64 + ni * 16 + frow][fk];
        #pragma unroll
        for (int mi = 0; mi < 4; ++mi)
            #pragma unroll
            for (int ni = 0; ni < 4; ++ni)
                acc[mi][ni] = __builtin_amdgcn_mfma_f32_16x16x32_bf16(
                    af[mi], bfr[ni], acc[mi][ni], 0, 0, 0);
    }

    const int drow = (lane >> 4) * 4;
    const int dcol = lane & 15;
    #pragma unroll
    for (int mi = 0; mi < 4; ++mi) {
        #pragma unroll
        for (int ni = 0; ni < 4; ++ni) {
            const int c = col0 + wn * 64 + ni * 16 + dcol;
            const float cs = (EPI == 1) ? colscale[c] : 0.0f;
            #pragma unroll
            for (int rg = 0; rg < 4; ++rg) {
                const int r = row0 + wm * 64 + mi * 16 + drow + rg;
                const float v = acc[mi][ni][rg];
                if (EPI == 1) Cf[(size_t)r * ldc + c] = v * cs;
                else          Cbp[(size_t)r * ldc + c] = f2bf(v);
            }
        }
    }
}

// ---------------------------------------------------------------------------
// Launch. Workspace (~120.1 MB):
//   kn    @   0M : 4096x2048 f32
//   Y     @  32M : 4096x2048 f32 (y, then residual in place)
//   Bbig  @  64M : 4096x4096 bf16  [ymse | sgn*sc_h | sgn*sc_l]
//   Abig  @  96M : 1024x4096 bf16  [q_rot | z_h | z_l]
//   Qb    @ 104M, Pib @ 108M, Sbh @ 116M, Sbl @ 118M : bf16 inputs
//   den   @ 120M, vnorm +16K, sc_h +32K, sc_l +48K
// ---------------------------------------------------------------------------
extern "C" void kernel_launch(void* const* d_in, const int* in_sizes, int n_in,
                              void* d_out, int out_size, void* d_ws, size_t ws_size,
                              hipStream_t stream)
{
    const float* queries = (const float*)d_in[0];
    const float* keys    = (const float*)d_in[1];
    const float* Pi      = (const float*)d_in[2];
    const float* ch      = (const float*)d_in[3];
    const float* cl      = (const float*)d_in[4];
    const float* S_high  = (const float*)d_in[5];
    const float* S_low   = (const float*)d_in[6];
    float* out = (float*)d_out;

    char* ws = (char*)d_ws;
    float*          kn    = (float*)(ws);
    float*          Y     = (float*)(ws + ((size_t)32 << 20));
    unsigned short* Bbig  = (unsigned short*)(ws + ((size_t)64 << 20));
    unsigned short* Abig  = (unsigned short*)(ws + ((size_t)96 << 20));
    unsigned short* Qb    = (unsigned short*)(ws + ((size_t)104 << 20));
    unsigned short* Pib   = (unsigned short*)(ws + ((size_t)108 << 20));
    unsigned short* Sbh   = (unsigned short*)(ws + ((size_t)116 << 20));
    unsigned short* Sbl   = (unsigned short*)(ws + ((size_t)118 << 20));
    float*          den   = (float*)(ws + ((size_t)120 << 20));
    float*          vnorm = (float*)(ws + ((size_t)120 << 20) + 16384);
    float*          sc_h  = (float*)(ws + ((size_t)120 << 20) + 32768);
    float*          sc_l  = (float*)(ws + ((size_t)120 << 20) + 49152);

    const double coefd = sqrt(M_PI / 2.0) / 1024.0;

    // numpy-exact norms
    norm_np_k<<<256, 256, 0, stream>>>(keys, den, vnorm);

    // decision-exact normalized keys
    kn_k<<<4096, 256, 0, stream>>>(keys, den, kn);

    // bf16 copies for the continuous MFMA path
    f2bf_k<<<1024, 256, 0, stream>>>(queries, Qb);
    f2bf_k<<<2048, 256, 0, stream>>>(Pi, Pib);
    f2bf_k<<<512, 256, 0, stream>>>(S_high, Sbh);
    f2bf_k<<<512, 256, 0, stream>>>(S_low, Sbl);

    // DECISION: Y = kn @ Pi^T  (f32 exact sequential chain, pk_fma)
    gemm_dec_k<0><<<dim3(16, 32, 1), 256, 0, stream>>>(
        kn, 2048, 0, Pi, Pi, 2048, Y, nullptr, 0, 2048, 2048, nullptr, nullptr);

    // DECISION: quantize -> residual in Y, bf16 ymse in Bbig, sc_h/sc_l
    quant_k<<<4096, 256, 0, stream>>>(Y, Bbig, ch, cl, sc_h, sc_l, coefd);

    // DECISION: scaled signs (z=0: high, z=1: low) -> bf16 into Bbig cols 2048+
    gemm_dec_k<1><<<dim3(8, 32, 2), 256, 0, stream>>>(
        Y, 2048, 1024, S_high, S_low, 1024,
        nullptr, Bbig + 2048, 1024, 4096, 1024, sc_h, sc_l);

    // CONTINUOUS (bf16 MFMA): Abig = [q_rot | z_h | z_l]
    gemm_mfma_k<2><<<dim3(16, 8, 1), 256, 0, stream>>>(
        Qb, 2048, 0, Pib, Pib, 2048, nullptr, Abig, 0, 4096, 2048, nullptr);
    gemm_mfma_k<2><<<dim3(8, 8, 2), 256, 0, stream>>>(
        Abig, 4096, 1024, Sbh, Sbl, 1024, nullptr, Abig + 2048, 1024, 4096, 1024, nullptr);

    // CONTINUOUS: out = (Abig @ Bbig^T) * vnorm[col]   (K=4096 fused)
    gemm_mfma_k<1><<<dim3(32, 8, 1), 256, 0, stream>>>(
        Abig, 4096, 0, Bbig, Bbig, 4096, out, nullptr, 0, 4096, 4096, vnorm);
}